// Round 8
// baseline (1149.243 us; speedup 1.0000x reference)
//
#include <hip/hip_runtime.h>
#include <hip/hip_bf16.h>
#include <math.h>

#define N_NODES 50000
#define N_EDGES 800000
#define DIN 41
#define H 192
#define CAP 64
#define NTILES 3125   // 50000 / 16

typedef __attribute__((ext_vector_type(8))) _Float16 f16x8;
typedef __attribute__((ext_vector_type(4))) float f32x4;

// ---------------- graph prep ----------------

__global__ void k_count(const int* __restrict__ ei, int* __restrict__ cnt) {
    int e = blockIdx.x * blockDim.x + threadIdx.x;
    if (e < N_EDGES) atomicAdd(&cnt[ei[N_EDGES + e]], 1);
}

__global__ void k_dis(const int* __restrict__ cnt, float* __restrict__ dis) {
    int i = blockIdx.x * blockDim.x + threadIdx.x;
    if (i < N_NODES) dis[i] = rsqrtf((float)(cnt[i] + 1));  // +1 self-loop
}

__global__ void k_fill(const int* __restrict__ ei, const float* __restrict__ dis,
                       int* __restrict__ cnt2, int* __restrict__ adj_src,
                       float* __restrict__ adj_coef) {
    int e = blockIdx.x * blockDim.x + threadIdx.x;
    if (e >= N_EDGES) return;
    int s = ei[e];
    int d = ei[N_EDGES + e];
    int slot = atomicAdd(&cnt2[d], 1);
    if (slot < CAP) {
        adj_src[d * CAP + slot] = s;
        adj_coef[d * CAP + slot] = dis[s] * dis[d];
    }
}

// weight transpose + fp16 two-term split: W [K][N] fp32 -> hi/lo [N][K] fp16
__global__ void k_wt(const float* __restrict__ W, _Float16* __restrict__ hi,
                     _Float16* __restrict__ lo, int K, int N) {
    int idx = blockIdx.x * blockDim.x + threadIdx.x;
    if (idx >= K * N) return;
    int n = idx / K, k = idx - n * K;
    float w = W[k * N + n];
    _Float16 h16 = (_Float16)w;
    hi[idx] = h16;
    lo[idx] = (_Float16)(w - (float)h16);
}

// ---------------- input projection: h = x @ W_in + b_in (fp32 + fp16 split) ----------------

__global__ void k_in(const float* __restrict__ x, const float* __restrict__ W,
                     const float* __restrict__ b, float* __restrict__ h,
                     _Float16* __restrict__ hhi, _Float16* __restrict__ hlo) {
    __shared__ float xs[DIN];
    int i = blockIdx.x;
    int j = threadIdx.x;
    if (j < DIN) xs[j] = x[i * DIN + j];
    __syncthreads();
    float acc = b[j];
#pragma unroll
    for (int k = 0; k < DIN; ++k) acc = fmaf(xs[k], W[k * H + j], acc);
    h[i * H + j] = acc;
    _Float16 v16 = (_Float16)acc;
    hhi[i * H + j] = v16;
    hlo[i * H + j] = (_Float16)(acc - (float)v16);
}

// ---------------- MFMA GEMM (fp16 dual-split, ~fp32 accuracy) ----------------
// C[50000 x NT*16] = (Ahi+Alo)[50000 x 192] @ (Bhi+Blo)^T, dropping lo*lo.
// A fp16 row-major [node][192]; Bt fp16 [NT*16][192] (N-major, k-contiguous).
// One wave per 16-node tile; 4 waves/block; B frags via L2 (72 KB, no LDS).
// Layouts (learn_hip m89/m97, dtype-independent): A/B frag = 16B contiguous/lane
// (row/col = lane&15, k0 = (lane>>4)*8); C/D col=lane&15, row=(lane>>4)*4+reg.

template <int NT, bool RELU, bool BIAS, bool SPLIT_OUT>
__global__ __launch_bounds__(256) void k_mfma_gemm(
    const _Float16* __restrict__ Ahi, const _Float16* __restrict__ Alo,
    const _Float16* __restrict__ Bhi, const _Float16* __restrict__ Blo,
    const float* __restrict__ bias, float* __restrict__ Cf,
    _Float16* __restrict__ Chi, _Float16* __restrict__ Clo) {
    const int wave = threadIdx.x >> 6;
    const int lane = threadIdx.x & 63;
    const int tile = blockIdx.x * 4 + wave;
    if (tile >= NTILES) return;
    const int row16 = lane & 15;
    const int kb = lane >> 4;            // 0..3
    const long nodeBase = (long)tile * 16;

    f16x8 ahi[6], alo[6];
    {
        const _Float16* ar = Ahi + (nodeBase + row16) * H + kb * 8;
        const _Float16* al = Alo + (nodeBase + row16) * H + kb * 8;
#pragma unroll
        for (int kt = 0; kt < 6; ++kt) {
            ahi[kt] = *(const f16x8*)(ar + kt * 32);
            alo[kt] = *(const f16x8*)(al + kt * 32);
        }
    }

    f32x4 acc[NT];
#pragma unroll
    for (int nt = 0; nt < NT; ++nt) acc[nt] = (f32x4){0.f, 0.f, 0.f, 0.f};

#pragma unroll
    for (int nt = 0; nt < NT; ++nt) {
        const _Float16* bh = Bhi + (nt * 16 + row16) * H + kb * 8;
        const _Float16* bl = Blo + (nt * 16 + row16) * H + kb * 8;
#pragma unroll
        for (int kt = 0; kt < 6; ++kt) {
            f16x8 bhf = *(const f16x8*)(bh + kt * 32);
            f16x8 blf = *(const f16x8*)(bl + kt * 32);
            acc[nt] = __builtin_amdgcn_mfma_f32_16x16x32_f16(ahi[kt], bhf, acc[nt], 0, 0, 0);
            acc[nt] = __builtin_amdgcn_mfma_f32_16x16x32_f16(alo[kt], bhf, acc[nt], 0, 0, 0);
            acc[nt] = __builtin_amdgcn_mfma_f32_16x16x32_f16(ahi[kt], blf, acc[nt], 0, 0, 0);
        }
    }

#pragma unroll
    for (int nt = 0; nt < NT; ++nt) {
        const int n = nt * 16 + row16;
        const float bs = BIAS ? bias[n] : 0.f;
#pragma unroll
        for (int r = 0; r < 4; ++r) {
            long node = nodeBase + kb * 4 + r;
            float v = acc[nt][r] + bs;
            if (RELU) v = fmaxf(v, 0.f);
            if (SPLIT_OUT) {
                _Float16 v16 = (_Float16)v;
                Chi[node * (NT * 16) + n] = v16;
                Clo[node * (NT * 16) + n] = (_Float16)(v - (float)v16);
            } else {
                Cf[node * (NT * 16) + n] = v;
            }
        }
    }
}

// ---------------- aggregation: h += relu(sum coef*m[src] + selfc*m[i] + bc) ----------------
// one wave per node; all fp32; regenerates the fp16 split of h on write-out

__global__ void k_agg(const float* __restrict__ m, float* __restrict__ h,
                      _Float16* __restrict__ hhi, _Float16* __restrict__ hlo,
                      const int* __restrict__ adj_src, const float* __restrict__ adj_coef,
                      const int* __restrict__ cnt, const float* __restrict__ dis,
                      const float* __restrict__ bc) {
    int gid = blockIdx.x * blockDim.x + threadIdx.x;
    int i = gid >> 6;
    int lane = threadIdx.x & 63;
    if (i >= N_NODES) return;

    float disi = dis[i];
    float selfc = disi * disi;
    const float* mi = m + (size_t)i * H;
    float a0 = selfc * mi[lane];
    float a1 = selfc * mi[lane + 64];
    float a2 = selfc * mi[lane + 128];

    int c = cnt[i];
    if (c > CAP) c = CAP;
    const int* as = adj_src + (size_t)i * CAP;
    const float* ac = adj_coef + (size_t)i * CAP;
    for (int e = 0; e < c; ++e) {
        int s = as[e];
        float cf = ac[e];
        const float* ms = m + (size_t)s * H;
        a0 = fmaf(cf, ms[lane], a0);
        a1 = fmaf(cf, ms[lane + 64], a1);
        a2 = fmaf(cf, ms[lane + 128], a2);
    }

    size_t base = (size_t)i * H;
    float h0 = h[base + lane]       + fmaxf(a0 + bc[lane], 0.f);
    float h1 = h[base + lane + 64]  + fmaxf(a1 + bc[lane + 64], 0.f);
    float h2 = h[base + lane + 128] + fmaxf(a2 + bc[lane + 128], 0.f);
    h[base + lane]       = h0;
    h[base + lane + 64]  = h1;
    h[base + lane + 128] = h2;
    _Float16 t0 = (_Float16)h0, t1 = (_Float16)h1, t2 = (_Float16)h2;
    hhi[base + lane]       = t0;  hlo[base + lane]       = (_Float16)(h0 - (float)t0);
    hhi[base + lane + 64]  = t1;  hlo[base + lane + 64]  = (_Float16)(h1 - (float)t1);
    hhi[base + lane + 128] = t2;  hlo[base + lane + 128] = (_Float16)(h2 - (float)t2);
}

// ---------------- final heads tail + normalize ----------------

__global__ void k_final(const float* __restrict__ p2, const float* __restrict__ r1,
                        const float* __restrict__ Wp3, const float* __restrict__ bp3,
                        const float* __restrict__ Wr2, const float* __restrict__ br2,
                        float* __restrict__ out) {
    int gid = blockIdx.x * blockDim.x + threadIdx.x;
    int i = gid >> 6;
    int lane = threadIdx.x & 63;
    if (i >= N_NODES) return;

    float s0 = 0.f, s1 = 0.f, sr = 0.f;
    for (int k = lane; k < 96; k += 64) {
        float pv = p2[(size_t)i * 96 + k];
        s0 = fmaf(pv, Wp3[k * 2 + 0], s0);
        s1 = fmaf(pv, Wp3[k * 2 + 1], s1);
        float rv = r1[(size_t)i * 96 + k];
        sr = fmaf(rv, Wr2[k], sr);
    }
#pragma unroll
    for (int off = 32; off > 0; off >>= 1) {
        s0 += __shfl_xor(s0, off);
        s1 += __shfl_xor(s1, off);
        sr += __shfl_xor(sr, off);
    }
    if (lane == 0) {
        s0 += bp3[0];
        s1 += bp3[1];
        float rad = 1.f / (1.f + expf(-(sr + br2[0])));
        float norm = sqrtf(s0 * s0 + s1 * s1 + 1e-8f);
        float inv = rad / norm;
        out[(size_t)i * 2 + 0] = s0 * inv;
        out[(size_t)i * 2 + 1] = s1 * inv;
    }
}

// ---------------- launch ----------------

extern "C" void kernel_launch(void* const* d_in, const int* in_sizes, int n_in,
                              void* d_out, int out_size, void* d_ws, size_t ws_size,
                              hipStream_t stream) {
    (void)in_sizes; (void)n_in; (void)out_size; (void)ws_size;

    const float* x    = (const float*)d_in[0];
    const int*   ei   = (const int*)d_in[1];
    const float* W_in = (const float*)d_in[2];
    const float* b_in = (const float*)d_in[3];
    const float* Wc   = (const float*)d_in[4];
    const float* bc   = (const float*)d_in[5];
    const float* Wp1  = (const float*)d_in[6];
    const float* bp1  = (const float*)d_in[7];
    const float* Wp2  = (const float*)d_in[8];
    const float* bp2  = (const float*)d_in[9];
    const float* Wp3  = (const float*)d_in[10];
    const float* bp3  = (const float*)d_in[11];
    const float* Wr1  = (const float*)d_in[12];
    const float* br1  = (const float*)d_in[13];
    const float* Wr2  = (const float*)d_in[14];
    const float* br2  = (const float*)d_in[15];
    float* out = (float*)d_out;

    char* ws = (char*)d_ws;
    float*     h        = (float*)    (ws + 0);            // 38,400,000
    float*     m        = (float*)    (ws + 38400000);     // 38,400,000
    float*     p2buf    = (float*)    (ws + 38400000);     // aliases m (dead after aggs)
    float*     r1buf    = (float*)    (ws + 57600000);     // aliases m upper half
    _Float16*  h_hi     = (_Float16*) (ws + 76800000);     // 19,200,000
    _Float16*  h_lo     = (_Float16*) (ws + 96000000);     // 19,200,000
    _Float16*  p1_hi    = (_Float16*) (ws + 115200000);    // 19,200,000
    _Float16*  p1_lo    = (_Float16*) (ws + 134400000);    // 19,200,000
    float*     dis      = (float*)    (ws + 153600000);    //    200,000
    int*       cnt      = (int*)      (ws + 153800000);    //    200,000
    int*       cnt2     = (int*)      (ws + 154000000);    //    200,000
    int*       adj_src  = (int*)      (ws + 154200000);    // 12,800,000
    float*     adj_coef = (float*)    (ws + 167000000);    // 12,800,000
    _Float16*  Wc_hi    = (_Float16*) (ws + 179800000);    // 294,912
    _Float16*  Wc_lo    = (_Float16*) (ws + 180094912);    // 294,912
    _Float16*  Wp1_hi   = (_Float16*) (ws + 180389824);    //  73,728
    _Float16*  Wp1_lo   = (_Float16*) (ws + 180463552);    //  73,728
    _Float16*  Wp2_hi   = (_Float16*) (ws + 180537280);    //  36,864
    _Float16*  Wp2_lo   = (_Float16*) (ws + 180574144);    //  36,864
    _Float16*  Wr1_hi   = (_Float16*) (ws + 180611008);    //  36,864
    _Float16*  Wr1_lo   = (_Float16*) (ws + 180647872);    //  36,864
    // total 180,684,736 bytes

    hipMemsetAsync(cnt, 0, 400000, stream);  // cnt + cnt2 (adjacent)

    const int EB = (N_EDGES + 255) / 256;
    const int NB = (N_NODES + 255) / 256;

    k_count<<<EB, 256, 0, stream>>>(ei, cnt);
    k_dis<<<NB, 256, 0, stream>>>(cnt, dis);
    k_fill<<<EB, 256, 0, stream>>>(ei, dis, cnt2, adj_src, adj_coef);

    // weight prep: [K][N] fp32 -> [N][K] fp16 hi/lo
    for (int l = 0; l < 4; ++l)
        k_wt<<<(H * H + 255) / 256, 256, 0, stream>>>(
            Wc + (size_t)l * H * H, Wc_hi + (size_t)l * H * H, Wc_lo + (size_t)l * H * H, H, H);
    k_wt<<<(H * H + 255) / 256, 256, 0, stream>>>(Wp1, Wp1_hi, Wp1_lo, H, H);
    k_wt<<<(H * 96 + 255) / 256, 256, 0, stream>>>(Wp2, Wp2_hi, Wp2_lo, H, 96);
    k_wt<<<(H * 96 + 255) / 256, 256, 0, stream>>>(Wr1, Wr1_hi, Wr1_lo, H, 96);

    k_in<<<N_NODES, H, 0, stream>>>(x, W_in, b_in, h, h_hi, h_lo);

    const int GB = (NTILES + 3) / 4;  // 782 blocks, 4 waves each
    for (int l = 0; l < 4; ++l) {
        k_mfma_gemm<12, false, false, false><<<GB, 256, 0, stream>>>(
            h_hi, h_lo, Wc_hi + (size_t)l * H * H, Wc_lo + (size_t)l * H * H,
            nullptr, m, nullptr, nullptr);
        k_agg<<<N_NODES / 4, 256, 0, stream>>>(m, h, h_hi, h_lo, adj_src, adj_coef,
                                               cnt, dis, bc + (size_t)l * H);
    }

    // heads
    k_mfma_gemm<12, true, true, true><<<GB, 256, 0, stream>>>(
        h_hi, h_lo, Wp1_hi, Wp1_lo, bp1, nullptr, p1_hi, p1_lo);
    k_mfma_gemm<6, true, true, false><<<GB, 256, 0, stream>>>(
        p1_hi, p1_lo, Wp2_hi, Wp2_lo, bp2, p2buf, nullptr, nullptr);
    k_mfma_gemm<6, true, true, false><<<GB, 256, 0, stream>>>(
        h_hi, h_lo, Wr1_hi, Wr1_lo, br1, r1buf, nullptr, nullptr);

    k_final<<<N_NODES / 4, 256, 0, stream>>>(p2buf, r1buf, Wp3, bp3, Wr2, br2, out);
}

// Round 9
// 1109.503 us; speedup vs baseline: 1.0358x; 1.0358x over previous
//
#include <hip/hip_runtime.h>
#include <hip/hip_bf16.h>
#include <math.h>

#define N_NODES 50000
#define N_EDGES 800000
#define DIN 41
#define H 192
#define CAP 64
#define NTILES 3125   // 50000 / 16

typedef __attribute__((ext_vector_type(8))) _Float16 f16x8;
typedef __attribute__((ext_vector_type(4))) float f32x4;

// ---------------- graph prep ----------------

__global__ void k_count(const int* __restrict__ ei, int* __restrict__ cnt) {
    int e = blockIdx.x * blockDim.x + threadIdx.x;
    if (e < N_EDGES) atomicAdd(&cnt[ei[N_EDGES + e]], 1);
}

__global__ void k_dis(const int* __restrict__ cnt, float* __restrict__ dis) {
    int i = blockIdx.x * blockDim.x + threadIdx.x;
    if (i < N_NODES) dis[i] = rsqrtf((float)(cnt[i] + 1));  // +1 self-loop
}

__global__ void k_fill(const int* __restrict__ ei, const float* __restrict__ dis,
                       int* __restrict__ cnt2, int* __restrict__ adj_src,
                       float* __restrict__ adj_coef) {
    int e = blockIdx.x * blockDim.x + threadIdx.x;
    if (e >= N_EDGES) return;
    int s = ei[e];
    int d = ei[N_EDGES + e];
    int slot = atomicAdd(&cnt2[d], 1);
    if (slot < CAP) {
        adj_src[d * CAP + slot] = s;
        adj_coef[d * CAP + slot] = dis[s] * dis[d];
    }
}

// weight transpose + fp16 two-term split: W [K][N] fp32 -> hi/lo [N][K] fp16
__global__ void k_wt(const float* __restrict__ W, _Float16* __restrict__ hi,
                     _Float16* __restrict__ lo, int K, int N) {
    int idx = blockIdx.x * blockDim.x + threadIdx.x;
    if (idx >= K * N) return;
    int n = idx / K, k = idx - n * K;
    float w = W[k * N + n];
    _Float16 h16 = (_Float16)w;
    hi[idx] = h16;
    lo[idx] = (_Float16)(w - (float)h16);
}

// ---------------- input projection: h = x @ W_in + b_in (fp16 split only) ----------------

__global__ void k_in(const float* __restrict__ x, const float* __restrict__ W,
                     const float* __restrict__ b,
                     _Float16* __restrict__ hhi, _Float16* __restrict__ hlo) {
    __shared__ float xs[DIN];
    int i = blockIdx.x;
    int j = threadIdx.x;
    if (j < DIN) xs[j] = x[i * DIN + j];
    __syncthreads();
    float acc = b[j];
#pragma unroll
    for (int k = 0; k < DIN; ++k) acc = fmaf(xs[k], W[k * H + j], acc);
    _Float16 v16 = (_Float16)acc;
    hhi[i * H + j] = v16;
    hlo[i * H + j] = (_Float16)(acc - (float)v16);
}

// ---------------- MFMA GEMM (fp16 dual-split, ~fp32 accuracy) ----------------
// C[50000 x NT*16] = (Ahi+Alo)[50000 x 192] @ (Bhi+Blo)^T, dropping lo*lo.
// kt OUTER / nt INNER: consecutive MFMAs target independent acc[nt] chains
// (pipelines at ~5cyc throughput instead of serializing on one acc's latency).

template <int NT, bool RELU, bool BIAS, bool SPLIT_OUT>
__global__ __launch_bounds__(256) void k_mfma_gemm(
    const _Float16* __restrict__ Ahi, const _Float16* __restrict__ Alo,
    const _Float16* __restrict__ Bhi, const _Float16* __restrict__ Blo,
    const float* __restrict__ bias, float* __restrict__ Cf,
    _Float16* __restrict__ Chi, _Float16* __restrict__ Clo) {
    const int wave = threadIdx.x >> 6;
    const int lane = threadIdx.x & 63;
    const int tile = blockIdx.x * 4 + wave;
    if (tile >= NTILES) return;
    const int row16 = lane & 15;
    const int kb = lane >> 4;            // 0..3
    const long nodeBase = (long)tile * 16;

    f16x8 ahi[6], alo[6];
    {
        const _Float16* ar = Ahi + (nodeBase + row16) * H + kb * 8;
        const _Float16* al = Alo + (nodeBase + row16) * H + kb * 8;
#pragma unroll
        for (int kt = 0; kt < 6; ++kt) {
            ahi[kt] = *(const f16x8*)(ar + kt * 32);
            alo[kt] = *(const f16x8*)(al + kt * 32);
        }
    }

    f32x4 acc[NT];
#pragma unroll
    for (int nt = 0; nt < NT; ++nt) acc[nt] = (f32x4){0.f, 0.f, 0.f, 0.f};

#pragma unroll
    for (int kt = 0; kt < 6; ++kt) {
#pragma unroll
        for (int nt = 0; nt < NT; ++nt) {
            const long boff = (long)(nt * 16 + row16) * H + kb * 8 + kt * 32;
            f16x8 bhf = *(const f16x8*)(Bhi + boff);
            f16x8 blf = *(const f16x8*)(Blo + boff);
            acc[nt] = __builtin_amdgcn_mfma_f32_16x16x32_f16(ahi[kt], bhf, acc[nt], 0, 0, 0);
            acc[nt] = __builtin_amdgcn_mfma_f32_16x16x32_f16(alo[kt], bhf, acc[nt], 0, 0, 0);
            acc[nt] = __builtin_amdgcn_mfma_f32_16x16x32_f16(ahi[kt], blf, acc[nt], 0, 0, 0);
        }
    }

#pragma unroll
    for (int nt = 0; nt < NT; ++nt) {
        const int n = nt * 16 + row16;
        const float bs = BIAS ? bias[n] : 0.f;
#pragma unroll
        for (int r = 0; r < 4; ++r) {
            long node = nodeBase + kb * 4 + r;
            float v = acc[nt][r] + bs;
            if (RELU) v = fmaxf(v, 0.f);
            if (SPLIT_OUT) {
                _Float16 v16 = (_Float16)v;
                Chi[node * (NT * 16) + n] = v16;
                Clo[node * (NT * 16) + n] = (_Float16)(v - (float)v16);
            } else {
                Cf[node * (NT * 16) + n] = v;
            }
        }
    }
}

// ---------------- aggregation: h += relu(sum coef*m[src] + selfc*m[i] + bc) ----------------
// one wave per node; 8-wide predicated neighbor batches for memory-level
// parallelism (the serial gather chain was the latency bottleneck: VALUBusy
// 11%, 2.9 TB/s). h lives as fp16 hi/lo split (reconstruct, update, re-split).

__global__ void k_agg(const float* __restrict__ m,
                      _Float16* __restrict__ hhi, _Float16* __restrict__ hlo,
                      const int* __restrict__ adj_src, const float* __restrict__ adj_coef,
                      const int* __restrict__ cnt, const float* __restrict__ dis,
                      const float* __restrict__ bc) {
    int gid = blockIdx.x * blockDim.x + threadIdx.x;
    int i = gid >> 6;
    int lane = threadIdx.x & 63;
    if (i >= N_NODES) return;

    float disi = dis[i];
    float selfc = disi * disi;
    const float* mi = m + (size_t)i * H;
    float a0 = selfc * mi[lane];
    float a1 = selfc * mi[lane + 64];
    float a2 = selfc * mi[lane + 128];

    int c = cnt[i];
    if (c > CAP) c = CAP;
    const int* as = adj_src + (size_t)i * CAP;
    const float* ac = adj_coef + (size_t)i * CAP;

    for (int e0 = 0; e0 < c; e0 += 8) {
        const float* mp[8];
        float cf[8];
#pragma unroll
        for (int u = 0; u < 8; ++u) {
            bool ok = (e0 + u) < c;
            int idx = ok ? (e0 + u) : 0;      // as[0] valid (loop entered => c>0)
            mp[u] = m + (size_t)as[idx] * H;
            cf[u] = ok ? ac[idx] : 0.f;
        }
        float v0[8], v1[8], v2[8];
#pragma unroll
        for (int u = 0; u < 8; ++u) {
            v0[u] = mp[u][lane];
            v1[u] = mp[u][lane + 64];
            v2[u] = mp[u][lane + 128];
        }
#pragma unroll
        for (int u = 0; u < 8; ++u) {
            a0 = fmaf(cf[u], v0[u], a0);
            a1 = fmaf(cf[u], v1[u], a1);
            a2 = fmaf(cf[u], v2[u], a2);
        }
    }

    size_t base = (size_t)i * H;
#pragma unroll
    for (int q = 0; q < 3; ++q) {
        size_t off = base + lane + q * 64;
        float agg = (q == 0) ? a0 : (q == 1) ? a1 : a2;
        float hv = (float)hhi[off] + (float)hlo[off] + fmaxf(agg + bc[lane + q * 64], 0.f);
        _Float16 t = (_Float16)hv;
        hhi[off] = t;
        hlo[off] = (_Float16)(hv - (float)t);
    }
}

// ---------------- final heads tail + normalize ----------------

__global__ void k_final(const float* __restrict__ p2, const float* __restrict__ r1,
                        const float* __restrict__ Wp3, const float* __restrict__ bp3,
                        const float* __restrict__ Wr2, const float* __restrict__ br2,
                        float* __restrict__ out) {
    int gid = blockIdx.x * blockDim.x + threadIdx.x;
    int i = gid >> 6;
    int lane = threadIdx.x & 63;
    if (i >= N_NODES) return;

    float s0 = 0.f, s1 = 0.f, sr = 0.f;
    for (int k = lane; k < 96; k += 64) {
        float pv = p2[(size_t)i * 96 + k];
        s0 = fmaf(pv, Wp3[k * 2 + 0], s0);
        s1 = fmaf(pv, Wp3[k * 2 + 1], s1);
        float rv = r1[(size_t)i * 96 + k];
        sr = fmaf(rv, Wr2[k], sr);
    }
#pragma unroll
    for (int off = 32; off > 0; off >>= 1) {
        s0 += __shfl_xor(s0, off);
        s1 += __shfl_xor(s1, off);
        sr += __shfl_xor(sr, off);
    }
    if (lane == 0) {
        s0 += bp3[0];
        s1 += bp3[1];
        float rad = 1.f / (1.f + expf(-(sr + br2[0])));
        float norm = sqrtf(s0 * s0 + s1 * s1 + 1e-8f);
        float inv = rad / norm;
        out[(size_t)i * 2 + 0] = s0 * inv;
        out[(size_t)i * 2 + 1] = s1 * inv;
    }
}

// ---------------- launch ----------------

extern "C" void kernel_launch(void* const* d_in, const int* in_sizes, int n_in,
                              void* d_out, int out_size, void* d_ws, size_t ws_size,
                              hipStream_t stream) {
    (void)in_sizes; (void)n_in; (void)out_size; (void)ws_size;

    const float* x    = (const float*)d_in[0];
    const int*   ei   = (const int*)d_in[1];
    const float* W_in = (const float*)d_in[2];
    const float* b_in = (const float*)d_in[3];
    const float* Wc   = (const float*)d_in[4];
    const float* bc   = (const float*)d_in[5];
    const float* Wp1  = (const float*)d_in[6];
    const float* bp1  = (const float*)d_in[7];
    const float* Wp2  = (const float*)d_in[8];
    const float* bp2  = (const float*)d_in[9];
    const float* Wp3  = (const float*)d_in[10];
    const float* bp3  = (const float*)d_in[11];
    const float* Wr1  = (const float*)d_in[12];
    const float* br1  = (const float*)d_in[13];
    const float* Wr2  = (const float*)d_in[14];
    const float* br2  = (const float*)d_in[15];
    float* out = (float*)d_out;

    char* ws = (char*)d_ws;
    float*     m        = (float*)    (ws + 0);            // 38,400,000
    float*     p2buf    = (float*)    (ws + 0);            // aliases m (dead after aggs)
    float*     r1buf    = (float*)    (ws + 19200000);     // aliases m upper half
    _Float16*  h_hi     = (_Float16*) (ws + 38400000);     // 19,200,000
    _Float16*  h_lo     = (_Float16*) (ws + 57600000);     // 19,200,000
    _Float16*  p1_hi    = (_Float16*) (ws + 76800000);     // 19,200,000
    _Float16*  p1_lo    = (_Float16*) (ws + 96000000);     // 19,200,000
    float*     dis      = (float*)    (ws + 115200000);    //    200,000
    int*       cnt      = (int*)      (ws + 115400000);    //    200,000
    int*       cnt2     = (int*)      (ws + 115600000);    //    200,000
    int*       adj_src  = (int*)      (ws + 115800000);    // 12,800,000
    float*     adj_coef = (float*)    (ws + 128600000);    // 12,800,000
    _Float16*  Wc_hi    = (_Float16*) (ws + 141400000);    // 294,912
    _Float16*  Wc_lo    = (_Float16*) (ws + 141694912);    // 294,912
    _Float16*  Wp1_hi   = (_Float16*) (ws + 141989824);    //  73,728
    _Float16*  Wp1_lo   = (_Float16*) (ws + 142063552);    //  73,728
    _Float16*  Wp2_hi   = (_Float16*) (ws + 142137280);    //  36,864
    _Float16*  Wp2_lo   = (_Float16*) (ws + 142174144);    //  36,864
    _Float16*  Wr1_hi   = (_Float16*) (ws + 142211008);    //  36,864
    _Float16*  Wr1_lo   = (_Float16*) (ws + 142247872);    //  36,864
    // total 142,284,736 bytes

    hipMemsetAsync(cnt, 0, 400000, stream);  // cnt + cnt2 (adjacent)

    const int EB = (N_EDGES + 255) / 256;
    const int NB = (N_NODES + 255) / 256;

    k_count<<<EB, 256, 0, stream>>>(ei, cnt);
    k_dis<<<NB, 256, 0, stream>>>(cnt, dis);
    k_fill<<<EB, 256, 0, stream>>>(ei, dis, cnt2, adj_src, adj_coef);

    // weight prep: [K][N] fp32 -> [N][K] fp16 hi/lo
    for (int l = 0; l < 4; ++l)
        k_wt<<<(H * H + 255) / 256, 256, 0, stream>>>(
            Wc + (size_t)l * H * H, Wc_hi + (size_t)l * H * H, Wc_lo + (size_t)l * H * H, H, H);
    k_wt<<<(H * H + 255) / 256, 256, 0, stream>>>(Wp1, Wp1_hi, Wp1_lo, H, H);
    k_wt<<<(H * 96 + 255) / 256, 256, 0, stream>>>(Wp2, Wp2_hi, Wp2_lo, H, 96);
    k_wt<<<(H * 96 + 255) / 256, 256, 0, stream>>>(Wr1, Wr1_hi, Wr1_lo, H, 96);

    k_in<<<N_NODES, H, 0, stream>>>(x, W_in, b_in, h_hi, h_lo);

    const int GB = (NTILES + 3) / 4;  // 782 blocks, 4 waves each
    for (int l = 0; l < 4; ++l) {
        k_mfma_gemm<12, false, false, false><<<GB, 256, 0, stream>>>(
            h_hi, h_lo, Wc_hi + (size_t)l * H * H, Wc_lo + (size_t)l * H * H,
            nullptr, m, nullptr, nullptr);
        k_agg<<<N_NODES / 4, 256, 0, stream>>>(m, h_hi, h_lo, adj_src, adj_coef,
                                               cnt, dis, bc + (size_t)l * H);
    }

    // heads
    k_mfma_gemm<12, true, true, true><<<GB, 256, 0, stream>>>(
        h_hi, h_lo, Wp1_hi, Wp1_lo, bp1, nullptr, p1_hi, p1_lo);
    k_mfma_gemm<6, true, true, false><<<GB, 256, 0, stream>>>(
        p1_hi, p1_lo, Wp2_hi, Wp2_lo, bp2, p2buf, nullptr, nullptr);
    k_mfma_gemm<6, true, true, false><<<GB, 256, 0, stream>>>(
        h_hi, h_lo, Wr1_hi, Wr1_lo, br1, r1buf, nullptr, nullptr);

    k_final<<<N_NODES / 4, 256, 0, stream>>>(p2buf, r1buf, Wp3, bp3, Wr2, br2, out);
}

// Round 11
// 1096.138 us; speedup vs baseline: 1.0484x; 1.0122x over previous
//
#include <hip/hip_runtime.h>
#include <hip/hip_bf16.h>
#include <math.h>

#define N_NODES 50000
#define N_EDGES 800000
#define DIN 41
#define H 192
#define CAP 64
#define NTILES 3125   // 50000 / 16

typedef __attribute__((ext_vector_type(8))) _Float16 f16x8;
typedef __attribute__((ext_vector_type(4))) float f32x4;

// ---------------- graph prep ----------------

__global__ void k_count(const int* __restrict__ ei, int* __restrict__ cnt) {
    int e = blockIdx.x * blockDim.x + threadIdx.x;
    if (e < N_EDGES) atomicAdd(&cnt[ei[N_EDGES + e]], 1);
}

__global__ void k_dis(const int* __restrict__ cnt, float* __restrict__ dis) {
    int i = blockIdx.x * blockDim.x + threadIdx.x;
    if (i < N_NODES) dis[i] = rsqrtf((float)(cnt[i] + 1));  // +1 self-loop
}

__global__ void k_fill(const int* __restrict__ ei, const float* __restrict__ dis,
                       int* __restrict__ cnt2, int* __restrict__ adj_src,
                       float* __restrict__ adj_coef) {
    int e = blockIdx.x * blockDim.x + threadIdx.x;
    if (e >= N_EDGES) return;
    int s = ei[e];
    int d = ei[N_EDGES + e];
    int slot = atomicAdd(&cnt2[d], 1);
    if (slot < CAP) {
        adj_src[d * CAP + slot] = s;
        adj_coef[d * CAP + slot] = dis[s] * dis[d];
    }
}

// weight transpose + fp16 two-term split: W [K][N] fp32 -> hi/lo [N][K] fp16
__global__ void k_wt(const float* __restrict__ W, _Float16* __restrict__ hi,
                     _Float16* __restrict__ lo, int K, int N) {
    int idx = blockIdx.x * blockDim.x + threadIdx.x;
    if (idx >= K * N) return;
    int n = idx / K, k = idx - n * K;
    float w = W[k * N + n];
    _Float16 h16 = (_Float16)w;
    hi[idx] = h16;
    lo[idx] = (_Float16)(w - (float)h16);
}

// ---------------- input projection: h = x @ W_in + b_in (fp16 split only) ----------------

__global__ void k_in(const float* __restrict__ x, const float* __restrict__ W,
                     const float* __restrict__ b,
                     _Float16* __restrict__ hhi, _Float16* __restrict__ hlo) {
    __shared__ float xs[DIN];
    int i = blockIdx.x;
    int j = threadIdx.x;
    if (j < DIN) xs[j] = x[i * DIN + j];
    __syncthreads();
    float acc = b[j];
#pragma unroll
    for (int k = 0; k < DIN; ++k) acc = fmaf(xs[k], W[k * H + j], acc);
    _Float16 v16 = (_Float16)acc;
    hhi[i * H + j] = v16;
    hlo[i * H + j] = (_Float16)(acc - (float)v16);
}

// ---------------- MFMA GEMM (fp16 dual-split, ~fp32 accuracy) ----------------
// C[50000 x NT*16] = (Ahi+Alo)[50000 x 192] @ (Bhi+Blo)^T, dropping lo*lo.
// kt OUTER / nt INNER: consecutive MFMAs target independent acc[nt] chains.

template <int NT, bool RELU, bool BIAS, bool SPLIT_OUT>
__global__ __launch_bounds__(256) void k_mfma_gemm(
    const _Float16* __restrict__ Ahi, const _Float16* __restrict__ Alo,
    const _Float16* __restrict__ Bhi, const _Float16* __restrict__ Blo,
    const float* __restrict__ bias, float* __restrict__ Cf,
    _Float16* __restrict__ Chi, _Float16* __restrict__ Clo) {
    const int wave = threadIdx.x >> 6;
    const int lane = threadIdx.x & 63;
    const int tile = blockIdx.x * 4 + wave;
    if (tile >= NTILES) return;
    const int row16 = lane & 15;
    const int kb = lane >> 4;            // 0..3
    const long nodeBase = (long)tile * 16;

    f16x8 ahi[6], alo[6];
    {
        const _Float16* ar = Ahi + (nodeBase + row16) * H + kb * 8;
        const _Float16* al = Alo + (nodeBase + row16) * H + kb * 8;
#pragma unroll
        for (int kt = 0; kt < 6; ++kt) {
            ahi[kt] = *(const f16x8*)(ar + kt * 32);
            alo[kt] = *(const f16x8*)(al + kt * 32);
        }
    }

    f32x4 acc[NT];
#pragma unroll
    for (int nt = 0; nt < NT; ++nt) acc[nt] = (f32x4){0.f, 0.f, 0.f, 0.f};

#pragma unroll
    for (int kt = 0; kt < 6; ++kt) {
#pragma unroll
        for (int nt = 0; nt < NT; ++nt) {
            const long boff = (long)(nt * 16 + row16) * H + kb * 8 + kt * 32;
            f16x8 bhf = *(const f16x8*)(Bhi + boff);
            f16x8 blf = *(const f16x8*)(Blo + boff);
            acc[nt] = __builtin_amdgcn_mfma_f32_16x16x32_f16(ahi[kt], bhf, acc[nt], 0, 0, 0);
            acc[nt] = __builtin_amdgcn_mfma_f32_16x16x32_f16(alo[kt], bhf, acc[nt], 0, 0, 0);
            acc[nt] = __builtin_amdgcn_mfma_f32_16x16x32_f16(ahi[kt], blf, acc[nt], 0, 0, 0);
        }
    }

#pragma unroll
    for (int nt = 0; nt < NT; ++nt) {
        const int n = nt * 16 + row16;
        const float bs = BIAS ? bias[n] : 0.f;
#pragma unroll
        for (int r = 0; r < 4; ++r) {
            long node = nodeBase + kb * 4 + r;
            float v = acc[nt][r] + bs;
            if (RELU) v = fmaxf(v, 0.f);
            if (SPLIT_OUT) {
                _Float16 v16 = (_Float16)v;
                Chi[node * (NT * 16) + n] = v16;
                Clo[node * (NT * 16) + n] = (_Float16)(v - (float)v16);
            } else {
                Cf[node * (NT * 16) + n] = v;
            }
        }
    }
}

// ---------------- aggregation ----------------
// One wave per node. 16-wide predicated neighbor batches; launch_bounds(256,4)
// gives a 128-VGPR budget so the compiler KEEPS the batch in registers
// (round 9: VGPR_Count=28 proved it re-rolled the loads into a serial
// latency chain -> 102us matched serial-latency arithmetic exactly).
// 32-bit element offsets (50000*192 < 2^31) cut address VGPRs in half.

__global__ __launch_bounds__(256, 4) void k_agg(
    const float* __restrict__ m,
    _Float16* __restrict__ hhi, _Float16* __restrict__ hlo,
    const int* __restrict__ adj_src, const float* __restrict__ adj_coef,
    const int* __restrict__ cnt, const float* __restrict__ dis,
    const float* __restrict__ bc) {
    int gid = blockIdx.x * blockDim.x + threadIdx.x;
    int i = gid >> 6;
    int lane = threadIdx.x & 63;
    if (i >= N_NODES) return;

    float disi = dis[i];
    float selfc = disi * disi;
    const float* mi = m + (size_t)i * H;
    float a0 = selfc * mi[lane];
    float a1 = selfc * mi[lane + 64];
    float a2 = selfc * mi[lane + 128];

    int c = cnt[i];
    if (c > CAP) c = CAP;
    const int* as = adj_src + (size_t)i * CAP;
    const float* ac = adj_coef + (size_t)i * CAP;

    for (int e0 = 0; e0 < c; e0 += 16) {
        int off[16];
        float cf[16];
#pragma unroll
        for (int u = 0; u < 16; ++u) {
            bool ok = (e0 + u) < c;
            int idx = ok ? (e0 + u) : 0;      // as[0] valid (loop entered => c>0)
            off[u] = as[idx] * H + lane;
            cf[u] = ok ? ac[idx] : 0.f;
        }
        float v0[16], v1[16], v2[16];
#pragma unroll
        for (int u = 0; u < 16; ++u) {
            v0[u] = m[off[u]];
            v1[u] = m[off[u] + 64];
            v2[u] = m[off[u] + 128];
        }
#pragma unroll
        for (int u = 0; u < 16; ++u) {
            a0 = fmaf(cf[u], v0[u], a0);
            a1 = fmaf(cf[u], v1[u], a1);
            a2 = fmaf(cf[u], v2[u], a2);
        }
    }

    size_t base = (size_t)i * H;
#pragma unroll
    for (int q = 0; q < 3; ++q) {
        size_t off = base + lane + q * 64;
        float agg = (q == 0) ? a0 : (q == 1) ? a1 : a2;
        float hv = (float)hhi[off] + (float)hlo[off] + fmaxf(agg + bc[lane + q * 64], 0.f);
        _Float16 t = (_Float16)hv;
        hhi[off] = t;
        hlo[off] = (_Float16)(hv - (float)t);
    }
}

// ---------------- final heads tail + normalize ----------------

__global__ void k_final(const float* __restrict__ p2, const float* __restrict__ r1,
                        const float* __restrict__ Wp3, const float* __restrict__ bp3,
                        const float* __restrict__ Wr2, const float* __restrict__ br2,
                        float* __restrict__ out) {
    int gid = blockIdx.x * blockDim.x + threadIdx.x;
    int i = gid >> 6;
    int lane = threadIdx.x & 63;
    if (i >= N_NODES) return;

    float s0 = 0.f, s1 = 0.f, sr = 0.f;
    for (int k = lane; k < 96; k += 64) {
        float pv = p2[(size_t)i * 96 + k];
        s0 = fmaf(pv, Wp3[k * 2 + 0], s0);
        s1 = fmaf(pv, Wp3[k * 2 + 1], s1);
        float rv = r1[(size_t)i * 96 + k];
        sr = fmaf(rv, Wr2[k], sr);
    }
#pragma unroll
    for (int off = 32; off > 0; off >>= 1) {
        s0 += __shfl_xor(s0, off);
        s1 += __shfl_xor(s1, off);
        sr += __shfl_xor(sr, off);
    }
    if (lane == 0) {
        s0 += bp3[0];
        s1 += bp3[1];
        float rad = 1.f / (1.f + expf(-(sr + br2[0])));
        float norm = sqrtf(s0 * s0 + s1 * s1 + 1e-8f);
        float inv = rad / norm;
        out[(size_t)i * 2 + 0] = s0 * inv;
        out[(size_t)i * 2 + 1] = s1 * inv;
    }
}

// ---------------- launch ----------------

extern "C" void kernel_launch(void* const* d_in, const int* in_sizes, int n_in,
                              void* d_out, int out_size, void* d_ws, size_t ws_size,
                              hipStream_t stream) {
    (void)in_sizes; (void)n_in; (void)out_size; (void)ws_size;

    const float* x    = (const float*)d_in[0];
    const int*   ei   = (const int*)d_in[1];
    const float* W_in = (const float*)d_in[2];
    const float* b_in = (const float*)d_in[3];
    const float* Wc   = (const float*)d_in[4];
    const float* bc   = (const float*)d_in[5];
    const float* Wp1  = (const float*)d_in[6];
    const float* bp1  = (const float*)d_in[7];
    const float* Wp2  = (const float*)d_in[8];
    const float* bp2  = (const float*)d_in[9];
    const float* Wp3  = (const float*)d_in[10];
    const float* bp3  = (const float*)d_in[11];
    const float* Wr1  = (const float*)d_in[12];
    const float* br1  = (const float*)d_in[13];
    const float* Wr2  = (const float*)d_in[14];
    const float* br2  = (const float*)d_in[15];
    float* out = (float*)d_out;

    char* ws = (char*)d_ws;
    float*     m        = (float*)    (ws + 0);            // 38,400,000
    float*     p2buf    = (float*)    (ws + 0);            // aliases m (dead after aggs)
    float*     r1buf    = (float*)    (ws + 19200000);     // aliases m upper half
    _Float16*  h_hi     = (_Float16*) (ws + 38400000);     // 19,200,000
    _Float16*  h_lo     = (_Float16*) (ws + 57600000);     // 19,200,000
    _Float16*  p1_hi    = (_Float16*) (ws + 76800000);     // 19,200,000
    _Float16*  p1_lo    = (_Float16*) (ws + 96000000);     // 19,200,000
    float*     dis      = (float*)    (ws + 115200000);    //    200,000
    int*       cnt      = (int*)      (ws + 115400000);    //    200,000
    int*       cnt2     = (int*)      (ws + 115600000);    //    200,000
    int*       adj_src  = (int*)      (ws + 115800000);    // 12,800,000
    float*     adj_coef = (float*)    (ws + 128600000);    // 12,800,000
    _Float16*  Wc_hi    = (_Float16*) (ws + 141400000);    // 294,912
    _Float16*  Wc_lo    = (_Float16*) (ws + 141694912);    // 294,912
    _Float16*  Wp1_hi   = (_Float16*) (ws + 141989824);    //  73,728
    _Float16*  Wp1_lo   = (_Float16*) (ws + 142063552);    //  73,728
    _Float16*  Wp2_hi   = (_Float16*) (ws + 142137280);    //  36,864
    _Float16*  Wp2_lo   = (_Float16*) (ws + 142174144);    //  36,864
    _Float16*  Wr1_hi   = (_Float16*) (ws + 142211008);    //  36,864
    _Float16*  Wr1_lo   = (_Float16*) (ws + 142247872);    //  36,864
    // total 142,284,736 bytes

    hipMemsetAsync(cnt, 0, 400000, stream);  // cnt + cnt2 (adjacent)

    const int EB = (N_EDGES + 255) / 256;
    const int NB = (N_NODES + 255) / 256;

    k_count<<<EB, 256, 0, stream>>>(ei, cnt);
    k_dis<<<NB, 256, 0, stream>>>(cnt, dis);
    k_fill<<<EB, 256, 0, stream>>>(ei, dis, cnt2, adj_src, adj_coef);

    // weight prep: [K][N] fp32 -> [N][K] fp16 hi/lo
    for (int l = 0; l < 4; ++l)
        k_wt<<<(H * H + 255) / 256, 256, 0, stream>>>(
            Wc + (size_t)l * H * H, Wc_hi + (size_t)l * H * H, Wc_lo + (size_t)l * H * H, H, H);
    k_wt<<<(H * H + 255) / 256, 256, 0, stream>>>(Wp1, Wp1_hi, Wp1_lo, H, H);
    k_wt<<<(H * 96 + 255) / 256, 256, 0, stream>>>(Wp2, Wp2_hi, Wp2_lo, H, 96);
    k_wt<<<(H * 96 + 255) / 256, 256, 0, stream>>>(Wr1, Wr1_hi, Wr1_lo, H, 96);

    k_in<<<N_NODES, H, 0, stream>>>(x, W_in, b_in, h_hi, h_lo);

    const int GB = (NTILES + 3) / 4;  // 782 blocks, 4 waves each
    for (int l = 0; l < 4; ++l) {
        k_mfma_gemm<12, false, false, false><<<GB, 256, 0, stream>>>(
            h_hi, h_lo, Wc_hi + (size_t)l * H * H, Wc_lo + (size_t)l * H * H,
            nullptr, m, nullptr, nullptr);
        k_agg<<<N_NODES / 4, 256, 0, stream>>>(m, h_hi, h_lo, adj_src, adj_coef,
                                               cnt, dis, bc + (size_t)l * H);
    }

    // heads
    k_mfma_gemm<12, true, true, true><<<GB, 256, 0, stream>>>(
        h_hi, h_lo, Wp1_hi, Wp1_lo, bp1, nullptr, p1_hi, p1_lo);
    k_mfma_gemm<6, true, true, false><<<GB, 256, 0, stream>>>(
        p1_hi, p1_lo, Wp2_hi, Wp2_lo, bp2, p2buf, nullptr, nullptr);
    k_mfma_gemm<6, true, true, false><<<GB, 256, 0, stream>>>(
        h_hi, h_lo, Wr1_hi, Wr1_lo, br1, r1buf, nullptr, nullptr);

    k_final<<<N_NODES / 4, 256, 0, stream>>>(p2buf, r1buf, Wp3, bp3, Wr2, br2, out);
}

// Round 12
// 891.743 us; speedup vs baseline: 1.2888x; 1.2292x over previous
//
#include <hip/hip_runtime.h>
#include <hip/hip_bf16.h>
#include <math.h>

#define N_NODES 50000
#define N_EDGES 800000
#define DIN 41
#define H 192
#define CAP 64
#define NTILES 3125   // 50000 / 16
#define NPAIRS 1563   // ceil(3125 / 2) -- 32-node wave tiles

typedef __attribute__((ext_vector_type(8))) _Float16 f16x8;
typedef __attribute__((ext_vector_type(4))) float f32x4;

// ---------------- graph prep ----------------

__global__ void k_count(const int* __restrict__ ei, int* __restrict__ cnt) {
    int e = blockIdx.x * blockDim.x + threadIdx.x;
    if (e < N_EDGES) atomicAdd(&cnt[ei[N_EDGES + e]], 1);
}

__global__ void k_dis(const int* __restrict__ cnt, float* __restrict__ dis) {
    int i = blockIdx.x * blockDim.x + threadIdx.x;
    if (i < N_NODES) dis[i] = rsqrtf((float)(cnt[i] + 1));  // +1 self-loop
}

// packed adjacency entry: .x = src node, .y = coef bits (one 8-B store
// instead of two 4-B RMWs 12.8 MB apart)
__global__ void k_fill(const int* __restrict__ ei, const float* __restrict__ dis,
                       int* __restrict__ cnt2, int2* __restrict__ adjp) {
    int e = blockIdx.x * blockDim.x + threadIdx.x;
    if (e >= N_EDGES) return;
    int s = ei[e];
    int d = ei[N_EDGES + e];
    int slot = atomicAdd(&cnt2[d], 1);
    if (slot < CAP) {
        adjp[d * CAP + slot] = make_int2(s, __float_as_int(dis[s] * dis[d]));
    }
}

// ---------------- fused weight prep: [K][N] fp32 -> [N][K] fp16 hi/lo ----------------
// one launch for Wc(4x192x192) + Wp1(192x192) + Wp2(192x96) + Wr1(192x96)

__global__ void k_wprep(const float* __restrict__ Wc, const float* __restrict__ Wp1,
                        const float* __restrict__ Wp2, const float* __restrict__ Wr1,
                        _Float16* __restrict__ Wc_hi, _Float16* __restrict__ Wc_lo,
                        _Float16* __restrict__ Wp1_hi, _Float16* __restrict__ Wp1_lo,
                        _Float16* __restrict__ Wp2_hi, _Float16* __restrict__ Wp2_lo,
                        _Float16* __restrict__ Wr1_hi, _Float16* __restrict__ Wr1_lo) {
    int idx = blockIdx.x * blockDim.x + threadIdx.x;
    const float* src; _Float16 *hi, *lo; int K, N, off;
    if (idx < 147456) {            // 4 x 36864
        int l = idx / 36864; off = idx - l * 36864;
        src = Wc + l * 36864; hi = Wc_hi + l * 36864; lo = Wc_lo + l * 36864; K = 192; N = 192;
    } else if (idx < 184320) {     // Wp1
        off = idx - 147456; src = Wp1; hi = Wp1_hi; lo = Wp1_lo; K = 192; N = 192;
    } else if (idx < 202752) {     // Wp2
        off = idx - 184320; src = Wp2; hi = Wp2_hi; lo = Wp2_lo; K = 192; N = 96;
    } else if (idx < 221184) {     // Wr1
        off = idx - 202752; src = Wr1; hi = Wr1_hi; lo = Wr1_lo; K = 192; N = 96;
    } else return;
    int n = off / K, k = off - n * K;
    float w = src[k * N + n];
    _Float16 h16 = (_Float16)w;
    hi[off] = h16;
    lo[off] = (_Float16)(w - (float)h16);
}

// ---------------- input projection: h = x @ W_in + b_in (fp16 split only) ----------------

__global__ void k_in(const float* __restrict__ x, const float* __restrict__ W,
                     const float* __restrict__ b,
                     _Float16* __restrict__ hhi, _Float16* __restrict__ hlo) {
    __shared__ float xs[DIN];
    int i = blockIdx.x;
    int j = threadIdx.x;
    if (j < DIN) xs[j] = x[i * DIN + j];
    __syncthreads();
    float acc = b[j];
#pragma unroll
    for (int k = 0; k < DIN; ++k) acc = fmaf(xs[k], W[k * H + j], acc);
    _Float16 v16 = (_Float16)acc;
    hhi[i * H + j] = v16;
    hlo[i * H + j] = (_Float16)(acc - (float)v16);
}

// ---------------- MFMA GEMM (fp16 dual-split, ~fp32 accuracy) ----------------
// TWO 16-node tiles per wave: the B fragments (the dominant load stream --
// 144 L2 loads/wave vs 24 A loads) are reused across both tiles' MFMAs,
// halving B traffic per node. A frags loaded per-kt to keep VGPR ~140.
// Per-acc MFMA sequence (kt outer, nt inner, hi*bh,lo*bh,hi*bl) identical
// to the verified round-11 kernel -> bit-identical results.

template <int NT, bool RELU, bool BIAS, bool SPLIT_OUT>
__global__ __launch_bounds__(256) void k_mfma_gemm(
    const _Float16* __restrict__ Ahi, const _Float16* __restrict__ Alo,
    const _Float16* __restrict__ Bhi, const _Float16* __restrict__ Blo,
    const float* __restrict__ bias, float* __restrict__ Cf,
    _Float16* __restrict__ Chi, _Float16* __restrict__ Clo) {
    const int wave = threadIdx.x >> 6;
    const int lane = threadIdx.x & 63;
    const int q = blockIdx.x * 4 + wave;          // tile-pair index
    if (q >= NPAIRS) return;
    const int t0 = 2 * q;
    const int t1 = 2 * q + 1;
    const bool has2 = (t1 < NTILES);
    const int row16 = lane & 15;
    const int kb = lane >> 4;                     // 0..3
    const long base0 = (long)t0 * 16;
    const long base1 = has2 ? (long)t1 * 16 : base0;   // keep addresses valid

    f32x4 acc0[NT], acc1[NT];
#pragma unroll
    for (int nt = 0; nt < NT; ++nt) {
        acc0[nt] = (f32x4){0.f, 0.f, 0.f, 0.f};
        acc1[nt] = (f32x4){0.f, 0.f, 0.f, 0.f};
    }

#pragma unroll
    for (int kt = 0; kt < 6; ++kt) {
        const long aoff0 = (base0 + row16) * H + kb * 8 + kt * 32;
        const long aoff1 = (base1 + row16) * H + kb * 8 + kt * 32;
        f16x8 a0h = *(const f16x8*)(Ahi + aoff0);
        f16x8 a0l = *(const f16x8*)(Alo + aoff0);
        f16x8 a1h = *(const f16x8*)(Ahi + aoff1);
        f16x8 a1l = *(const f16x8*)(Alo + aoff1);
#pragma unroll
        for (int nt = 0; nt < NT; ++nt) {
            const long boff = (long)(nt * 16 + row16) * H + kb * 8 + kt * 32;
            f16x8 bhf = *(const f16x8*)(Bhi + boff);
            f16x8 blf = *(const f16x8*)(Blo + boff);
            acc0[nt] = __builtin_amdgcn_mfma_f32_16x16x32_f16(a0h, bhf, acc0[nt], 0, 0, 0);
            acc0[nt] = __builtin_amdgcn_mfma_f32_16x16x32_f16(a0l, bhf, acc0[nt], 0, 0, 0);
            acc0[nt] = __builtin_amdgcn_mfma_f32_16x16x32_f16(a0h, blf, acc0[nt], 0, 0, 0);
            acc1[nt] = __builtin_amdgcn_mfma_f32_16x16x32_f16(a1h, bhf, acc1[nt], 0, 0, 0);
            acc1[nt] = __builtin_amdgcn_mfma_f32_16x16x32_f16(a1l, bhf, acc1[nt], 0, 0, 0);
            acc1[nt] = __builtin_amdgcn_mfma_f32_16x16x32_f16(a1h, blf, acc1[nt], 0, 0, 0);
        }
    }

#pragma unroll
    for (int nt = 0; nt < NT; ++nt) {
        const int n = nt * 16 + row16;
        const float bs = BIAS ? bias[n] : 0.f;
#pragma unroll
        for (int r = 0; r < 4; ++r) {
            long node = base0 + kb * 4 + r;
            float v = acc0[nt][r] + bs;
            if (RELU) v = fmaxf(v, 0.f);
            if (SPLIT_OUT) {
                _Float16 v16 = (_Float16)v;
                Chi[node * (NT * 16) + n] = v16;
                Clo[node * (NT * 16) + n] = (_Float16)(v - (float)v16);
            } else {
                Cf[node * (NT * 16) + n] = v;
            }
        }
        if (has2) {
#pragma unroll
            for (int r = 0; r < 4; ++r) {
                long node = base1 + kb * 4 + r;
                float v = acc1[nt][r] + bs;
                if (RELU) v = fmaxf(v, 0.f);
                if (SPLIT_OUT) {
                    _Float16 v16 = (_Float16)v;
                    Chi[node * (NT * 16) + n] = v16;
                    Clo[node * (NT * 16) + n] = (_Float16)(v - (float)v16);
                } else {
                    Cf[node * (NT * 16) + n] = v;
                }
            }
        }
    }
}

// ---------------- aggregation (unchanged from round 11: 97.5us, pattern floor) ----------------

__global__ __launch_bounds__(256, 4) void k_agg(
    const float* __restrict__ m,
    _Float16* __restrict__ hhi, _Float16* __restrict__ hlo,
    const int2* __restrict__ adjp,
    const int* __restrict__ cnt, const float* __restrict__ dis,
    const float* __restrict__ bc) {
    int gid = blockIdx.x * blockDim.x + threadIdx.x;
    int i = gid >> 6;
    int lane = threadIdx.x & 63;
    if (i >= N_NODES) return;

    float disi = dis[i];
    float selfc = disi * disi;
    const float* mi = m + (size_t)i * H;
    float a0 = selfc * mi[lane];
    float a1 = selfc * mi[lane + 64];
    float a2 = selfc * mi[lane + 128];

    int c = cnt[i];
    if (c > CAP) c = CAP;
    const int2* ap = adjp + (size_t)i * CAP;

    for (int e0 = 0; e0 < c; e0 += 16) {
        int off[16];
        float cf[16];
#pragma unroll
        for (int u = 0; u < 16; ++u) {
            bool ok = (e0 + u) < c;
            int idx = ok ? (e0 + u) : 0;
            int2 ent = ap[idx];
            off[u] = ent.x * H + lane;
            cf[u] = ok ? __int_as_float(ent.y) : 0.f;
        }
        float v0[16], v1[16], v2[16];
#pragma unroll
        for (int u = 0; u < 16; ++u) {
            v0[u] = m[off[u]];
            v1[u] = m[off[u] + 64];
            v2[u] = m[off[u] + 128];
        }
#pragma unroll
        for (int u = 0; u < 16; ++u) {
            a0 = fmaf(cf[u], v0[u], a0);
            a1 = fmaf(cf[u], v1[u], a1);
            a2 = fmaf(cf[u], v2[u], a2);
        }
    }

    size_t base = (size_t)i * H;
#pragma unroll
    for (int q = 0; q < 3; ++q) {
        size_t off = base + lane + q * 64;
        float agg = (q == 0) ? a0 : (q == 1) ? a1 : a2;
        float hv = (float)hhi[off] + (float)hlo[off] + fmaxf(agg + bc[lane + q * 64], 0.f);
        _Float16 t = (_Float16)hv;
        hhi[off] = t;
        hlo[off] = (_Float16)(hv - (float)t);
    }
}

// ---------------- final heads tail + normalize ----------------

__global__ void k_final(const float* __restrict__ p2, const float* __restrict__ r1,
                        const float* __restrict__ Wp3, const float* __restrict__ bp3,
                        const float* __restrict__ Wr2, const float* __restrict__ br2,
                        float* __restrict__ out) {
    int gid = blockIdx.x * blockDim.x + threadIdx.x;
    int i = gid >> 6;
    int lane = threadIdx.x & 63;
    if (i >= N_NODES) return;

    float s0 = 0.f, s1 = 0.f, sr = 0.f;
    for (int k = lane; k < 96; k += 64) {
        float pv = p2[(size_t)i * 96 + k];
        s0 = fmaf(pv, Wp3[k * 2 + 0], s0);
        s1 = fmaf(pv, Wp3[k * 2 + 1], s1);
        float rv = r1[(size_t)i * 96 + k];
        sr = fmaf(rv, Wr2[k], sr);
    }
#pragma unroll
    for (int off = 32; off > 0; off >>= 1) {
        s0 += __shfl_xor(s0, off);
        s1 += __shfl_xor(s1, off);
        sr += __shfl_xor(sr, off);
    }
    if (lane == 0) {
        s0 += bp3[0];
        s1 += bp3[1];
        float rad = 1.f / (1.f + expf(-(sr + br2[0])));
        float norm = sqrtf(s0 * s0 + s1 * s1 + 1e-8f);
        float inv = rad / norm;
        out[(size_t)i * 2 + 0] = s0 * inv;
        out[(size_t)i * 2 + 1] = s1 * inv;
    }
}

// ---------------- launch ----------------

extern "C" void kernel_launch(void* const* d_in, const int* in_sizes, int n_in,
                              void* d_out, int out_size, void* d_ws, size_t ws_size,
                              hipStream_t stream) {
    (void)in_sizes; (void)n_in; (void)out_size; (void)ws_size;

    const float* x    = (const float*)d_in[0];
    const int*   ei   = (const int*)d_in[1];
    const float* W_in = (const float*)d_in[2];
    const float* b_in = (const float*)d_in[3];
    const float* Wc   = (const float*)d_in[4];
    const float* bc   = (const float*)d_in[5];
    const float* Wp1  = (const float*)d_in[6];
    const float* bp1  = (const float*)d_in[7];
    const float* Wp2  = (const float*)d_in[8];
    const float* bp2  = (const float*)d_in[9];
    const float* Wp3  = (const float*)d_in[10];
    const float* bp3  = (const float*)d_in[11];
    const float* Wr1  = (const float*)d_in[12];
    const float* br1  = (const float*)d_in[13];
    const float* Wr2  = (const float*)d_in[14];
    const float* br2  = (const float*)d_in[15];
    float* out = (float*)d_out;

    char* ws = (char*)d_ws;
    float*     m        = (float*)    (ws + 0);            // 38,400,000
    float*     p2buf    = (float*)    (ws + 0);            // aliases m (dead after aggs)
    float*     r1buf    = (float*)    (ws + 19200000);     // aliases m upper half
    _Float16*  h_hi     = (_Float16*) (ws + 38400000);     // 19,200,000
    _Float16*  h_lo     = (_Float16*) (ws + 57600000);     // 19,200,000
    _Float16*  p1_hi    = (_Float16*) (ws + 76800000);     // 19,200,000
    _Float16*  p1_lo    = (_Float16*) (ws + 96000000);     // 19,200,000
    float*     dis      = (float*)    (ws + 115200000);    //    200,000
    int*       cnt      = (int*)      (ws + 115400000);    //    200,000
    int*       cnt2     = (int*)      (ws + 115600000);    //    200,000
    int2*      adjp     = (int2*)     (ws + 115800000);    // 25,600,000 (packed src+coef)
    _Float16*  Wc_hi    = (_Float16*) (ws + 141400000);    // 294,912
    _Float16*  Wc_lo    = (_Float16*) (ws + 141694912);    // 294,912
    _Float16*  Wp1_hi   = (_Float16*) (ws + 141989824);    //  73,728
    _Float16*  Wp1_lo   = (_Float16*) (ws + 142063552);    //  73,728
    _Float16*  Wp2_hi   = (_Float16*) (ws + 142137280);    //  36,864
    _Float16*  Wp2_lo   = (_Float16*) (ws + 142174144);    //  36,864
    _Float16*  Wr1_hi   = (_Float16*) (ws + 142211008);    //  36,864
    _Float16*  Wr1_lo   = (_Float16*) (ws + 142247872);    //  36,864
    // total 142,284,736 bytes

    hipMemsetAsync(cnt, 0, 400000, stream);  // cnt + cnt2 (adjacent)

    const int EB = (N_EDGES + 255) / 256;
    const int NB = (N_NODES + 255) / 256;

    k_count<<<EB, 256, 0, stream>>>(ei, cnt);
    k_dis<<<NB, 256, 0, stream>>>(cnt, dis);
    k_fill<<<EB, 256, 0, stream>>>(ei, dis, cnt2, adjp);

    k_wprep<<<(221184 + 255) / 256, 256, 0, stream>>>(
        Wc, Wp1, Wp2, Wr1, Wc_hi, Wc_lo, Wp1_hi, Wp1_lo,
        Wp2_hi, Wp2_lo, Wr1_hi, Wr1_lo);

    k_in<<<N_NODES, H, 0, stream>>>(x, W_in, b_in, h_hi, h_lo);

    const int GB2 = (NPAIRS + 3) / 4;  // 391 blocks, 4 waves (2 tiles each)
    for (int l = 0; l < 4; ++l) {
        k_mfma_gemm<12, false, false, false><<<GB2, 256, 0, stream>>>(
            h_hi, h_lo, Wc_hi + (size_t)l * H * H, Wc_lo + (size_t)l * H * H,
            nullptr, m, nullptr, nullptr);
        k_agg<<<N_NODES / 4, 256, 0, stream>>>(m, h_hi, h_lo, adjp,
                                               cnt, dis, bc + (size_t)l * H);
    }

    // heads
    k_mfma_gemm<12, true, true, true><<<GB2, 256, 0, stream>>>(
        h_hi, h_lo, Wp1_hi, Wp1_lo, bp1, nullptr, p1_hi, p1_lo);
    k_mfma_gemm<6, true, true, false><<<GB2, 256, 0, stream>>>(
        p1_hi, p1_lo, Wp2_hi, Wp2_lo, bp2, p2buf, nullptr, nullptr);
    k_mfma_gemm<6, true, true, false><<<GB2, 256, 0, stream>>>(
        h_hi, h_lo, Wr1_hi, Wr1_lo, br1, r1buf, nullptr, nullptr);

    k_final<<<N_NODES / 4, 256, 0, stream>>>(p2buf, r1buf, Wp3, bp3, Wr2, br2, out);
}

// Round 14
// 802.613 us; speedup vs baseline: 1.4319x; 1.1110x over previous
//
#include <hip/hip_runtime.h>
#include <hip/hip_bf16.h>
#include <math.h>

#define N_NODES 50000
#define N_EDGES 800000
#define DIN 41
#define H 192
#define CAP 64
#define NTILES 3125   // 50000 / 16
#define NPAIRS 1563   // ceil(3125 / 2) -- 32-node wave tiles

typedef __attribute__((ext_vector_type(8))) _Float16 f16x8;
typedef __attribute__((ext_vector_type(4))) float f32x4;

// ---------------- graph prep ----------------

__global__ void k_count(const int* __restrict__ ei, int* __restrict__ cnt) {
    int e = blockIdx.x * blockDim.x + threadIdx.x;
    if (e < N_EDGES) atomicAdd(&cnt[ei[N_EDGES + e]], 1);
}

__global__ void k_dis(const int* __restrict__ cnt, float* __restrict__ dis) {
    int i = blockIdx.x * blockDim.x + threadIdx.x;
    if (i < N_NODES) dis[i] = rsqrtf((float)(cnt[i] + 1));  // +1 self-loop
}

// packed adjacency entry: .x = src node, .y = coef bits
__global__ void k_fill(const int* __restrict__ ei, const float* __restrict__ dis,
                       int* __restrict__ cnt2, int2* __restrict__ adjp) {
    int e = blockIdx.x * blockDim.x + threadIdx.x;
    if (e >= N_EDGES) return;
    int s = ei[e];
    int d = ei[N_EDGES + e];
    int slot = atomicAdd(&cnt2[d], 1);
    if (slot < CAP) {
        adjp[d * CAP + slot] = make_int2(s, __float_as_int(dis[s] * dis[d]));
    }
}

// ---------------- fused weight prep: [K][N] fp32 -> [N][K] fp16 hi/lo ----------------

__global__ void k_wprep(const float* __restrict__ Wc, const float* __restrict__ Wp1,
                        const float* __restrict__ Wp2, const float* __restrict__ Wr1,
                        _Float16* __restrict__ Wc_hi, _Float16* __restrict__ Wc_lo,
                        _Float16* __restrict__ Wp1_hi, _Float16* __restrict__ Wp1_lo,
                        _Float16* __restrict__ Wp2_hi, _Float16* __restrict__ Wp2_lo,
                        _Float16* __restrict__ Wr1_hi, _Float16* __restrict__ Wr1_lo) {
    int idx = blockIdx.x * blockDim.x + threadIdx.x;
    const float* src; _Float16 *hi, *lo; int K, N, off;
    if (idx < 147456) {            // 4 x 36864
        int l = idx / 36864; off = idx - l * 36864;
        src = Wc + l * 36864; hi = Wc_hi + l * 36864; lo = Wc_lo + l * 36864; K = 192; N = 192;
    } else if (idx < 184320) {     // Wp1
        off = idx - 147456; src = Wp1; hi = Wp1_hi; lo = Wp1_lo; K = 192; N = 192;
    } else if (idx < 202752) {     // Wp2
        off = idx - 184320; src = Wp2; hi = Wp2_hi; lo = Wp2_lo; K = 192; N = 96;
    } else if (idx < 221184) {     // Wr1
        off = idx - 202752; src = Wr1; hi = Wr1_hi; lo = Wr1_lo; K = 192; N = 96;
    } else return;
    int n = off / K, k = off - n * K;
    float w = src[k * N + n];
    _Float16 h16 = (_Float16)w;
    hi[off] = h16;
    lo[off] = (_Float16)(w - (float)h16);
}

// ---------------- input projection: h = x @ W_in + b_in (fp16 split only) ----------------

__global__ void k_in(const float* __restrict__ x, const float* __restrict__ W,
                     const float* __restrict__ b,
                     _Float16* __restrict__ hhi, _Float16* __restrict__ hlo) {
    __shared__ float xs[DIN];
    int i = blockIdx.x;
    int j = threadIdx.x;
    if (j < DIN) xs[j] = x[i * DIN + j];
    __syncthreads();
    float acc = b[j];
#pragma unroll
    for (int k = 0; k < DIN; ++k) acc = fmaf(xs[k], W[k * H + j], acc);
    _Float16 v16 = (_Float16)acc;
    hhi[i * H + j] = v16;
    hlo[i * H + j] = (_Float16)(acc - (float)v16);
}

// ---------------- MFMA GEMM (fp16 dual-split, ~fp32 accuracy) ----------------
// Two 16-node tiles per wave (B-fragment reuse, verified round 12: -200us).
// F16COPY additionally stores an fp16 cast of C for the agg gather path.

template <int NT, bool RELU, bool BIAS, bool SPLIT_OUT, bool F16COPY>
__global__ __launch_bounds__(256) void k_mfma_gemm(
    const _Float16* __restrict__ Ahi, const _Float16* __restrict__ Alo,
    const _Float16* __restrict__ Bhi, const _Float16* __restrict__ Blo,
    const float* __restrict__ bias, float* __restrict__ Cf,
    _Float16* __restrict__ Chi, _Float16* __restrict__ Clo,
    _Float16* __restrict__ C16) {
    const int wave = threadIdx.x >> 6;
    const int lane = threadIdx.x & 63;
    const int q = blockIdx.x * 4 + wave;          // tile-pair index
    if (q >= NPAIRS) return;
    const int t0 = 2 * q;
    const int t1 = 2 * q + 1;
    const bool has2 = (t1 < NTILES);
    const int row16 = lane & 15;
    const int kb = lane >> 4;                     // 0..3
    const long base0 = (long)t0 * 16;
    const long base1 = has2 ? (long)t1 * 16 : base0;

    f32x4 acc0[NT], acc1[NT];
#pragma unroll
    for (int nt = 0; nt < NT; ++nt) {
        acc0[nt] = (f32x4){0.f, 0.f, 0.f, 0.f};
        acc1[nt] = (f32x4){0.f, 0.f, 0.f, 0.f};
    }

#pragma unroll
    for (int kt = 0; kt < 6; ++kt) {
        const long aoff0 = (base0 + row16) * H + kb * 8 + kt * 32;
        const long aoff1 = (base1 + row16) * H + kb * 8 + kt * 32;
        f16x8 a0h = *(const f16x8*)(Ahi + aoff0);
        f16x8 a0l = *(const f16x8*)(Alo + aoff0);
        f16x8 a1h = *(const f16x8*)(Ahi + aoff1);
        f16x8 a1l = *(const f16x8*)(Alo + aoff1);
#pragma unroll
        for (int nt = 0; nt < NT; ++nt) {
            const long boff = (long)(nt * 16 + row16) * H + kb * 8 + kt * 32;
            f16x8 bhf = *(const f16x8*)(Bhi + boff);
            f16x8 blf = *(const f16x8*)(Blo + boff);
            acc0[nt] = __builtin_amdgcn_mfma_f32_16x16x32_f16(a0h, bhf, acc0[nt], 0, 0, 0);
            acc0[nt] = __builtin_amdgcn_mfma_f32_16x16x32_f16(a0l, bhf, acc0[nt], 0, 0, 0);
            acc0[nt] = __builtin_amdgcn_mfma_f32_16x16x32_f16(a0h, blf, acc0[nt], 0, 0, 0);
            acc1[nt] = __builtin_amdgcn_mfma_f32_16x16x32_f16(a1h, bhf, acc1[nt], 0, 0, 0);
            acc1[nt] = __builtin_amdgcn_mfma_f32_16x16x32_f16(a1l, bhf, acc1[nt], 0, 0, 0);
            acc1[nt] = __builtin_amdgcn_mfma_f32_16x16x32_f16(a1h, blf, acc1[nt], 0, 0, 0);
        }
    }

#pragma unroll
    for (int nt = 0; nt < NT; ++nt) {
        const int n = nt * 16 + row16;
        const float bs = BIAS ? bias[n] : 0.f;
#pragma unroll
        for (int r = 0; r < 4; ++r) {
            long node = base0 + kb * 4 + r;
            float v = acc0[nt][r] + bs;
            if (RELU) v = fmaxf(v, 0.f);
            if (SPLIT_OUT) {
                _Float16 v16 = (_Float16)v;
                Chi[node * (NT * 16) + n] = v16;
                Clo[node * (NT * 16) + n] = (_Float16)(v - (float)v16);
            } else {
                Cf[node * (NT * 16) + n] = v;
                if (F16COPY) C16[node * (NT * 16) + n] = (_Float16)v;
            }
        }
        if (has2) {
#pragma unroll
            for (int r = 0; r < 4; ++r) {
                long node = base1 + kb * 4 + r;
                float v = acc1[nt][r] + bs;
                if (RELU) v = fmaxf(v, 0.f);
                if (SPLIT_OUT) {
                    _Float16 v16 = (_Float16)v;
                    Chi[node * (NT * 16) + n] = v16;
                    Clo[node * (NT * 16) + n] = (_Float16)(v - (float)v16);
                } else {
                    Cf[node * (NT * 16) + n] = v;
                    if (F16COPY) C16[node * (NT * 16) + n] = (_Float16)v;
                }
            }
        }
    }
}

// ---------------- aggregation ----------------
// Neighbor gathers read the fp16 copy of m (half the cache lines per random
// row: 128B vs 256B -> FETCH 318->~200MB). Self term keeps fp32 m (largest
// coef 1/deg, up to 1.0; neighbor coefs ~0.06 so their fp16 error ~1e-4*|m|).

__global__ __launch_bounds__(256, 4) void k_agg(
    const float* __restrict__ m, const _Float16* __restrict__ m16,
    _Float16* __restrict__ hhi, _Float16* __restrict__ hlo,
    const int2* __restrict__ adjp,
    const int* __restrict__ cnt, const float* __restrict__ dis,
    const float* __restrict__ bc) {
    int gid = blockIdx.x * blockDim.x + threadIdx.x;
    int i = gid >> 6;
    int lane = threadIdx.x & 63;
    if (i >= N_NODES) return;

    float disi = dis[i];
    float selfc = disi * disi;
    const float* mi = m + (size_t)i * H;
    float a0 = selfc * mi[lane];
    float a1 = selfc * mi[lane + 64];
    float a2 = selfc * mi[lane + 128];

    int c = cnt[i];
    if (c > CAP) c = CAP;
    const int2* ap = adjp + (size_t)i * CAP;

    for (int e0 = 0; e0 < c; e0 += 16) {
        int off[16];
        float cf[16];
#pragma unroll
        for (int u = 0; u < 16; ++u) {
            bool ok = (e0 + u) < c;
            int idx = ok ? (e0 + u) : 0;
            int2 ent = ap[idx];
            off[u] = ent.x * H + lane;
            cf[u] = ok ? __int_as_float(ent.y) : 0.f;
        }
        float v0[16], v1[16], v2[16];
#pragma unroll
        for (int u = 0; u < 16; ++u) {
            v0[u] = (float)m16[off[u]];
            v1[u] = (float)m16[off[u] + 64];
            v2[u] = (float)m16[off[u] + 128];
        }
#pragma unroll
        for (int u = 0; u < 16; ++u) {
            a0 = fmaf(cf[u], v0[u], a0);
            a1 = fmaf(cf[u], v1[u], a1);
            a2 = fmaf(cf[u], v2[u], a2);
        }
    }

    size_t base = (size_t)i * H;
#pragma unroll
    for (int q = 0; q < 3; ++q) {
        size_t off = base + lane + q * 64;
        float agg = (q == 0) ? a0 : (q == 1) ? a1 : a2;
        float hv = (float)hhi[off] + (float)hlo[off] + fmaxf(agg + bc[lane + q * 64], 0.f);
        _Float16 t = (_Float16)hv;
        hhi[off] = t;
        hlo[off] = (_Float16)(hv - (float)t);
    }
}

// ---------------- final heads tail + normalize ----------------

__global__ void k_final(const float* __restrict__ p2, const float* __restrict__ r1,
                        const float* __restrict__ Wp3, const float* __restrict__ bp3,
                        const float* __restrict__ Wr2, const float* __restrict__ br2,
                        float* __restrict__ out) {
    int gid = blockIdx.x * blockDim.x + threadIdx.x;
    int i = gid >> 6;
    int lane = threadIdx.x & 63;
    if (i >= N_NODES) return;

    float s0 = 0.f, s1 = 0.f, sr = 0.f;
    for (int k = lane; k < 96; k += 64) {
        float pv = p2[(size_t)i * 96 + k];
        s0 = fmaf(pv, Wp3[k * 2 + 0], s0);
        s1 = fmaf(pv, Wp3[k * 2 + 1], s1);
        float rv = r1[(size_t)i * 96 + k];
        sr = fmaf(rv, Wr2[k], sr);
    }
#pragma unroll
    for (int off = 32; off > 0; off >>= 1) {
        s0 += __shfl_xor(s0, off);
        s1 += __shfl_xor(s1, off);
        sr += __shfl_xor(sr, off);
    }
    if (lane == 0) {
        s0 += bp3[0];
        s1 += bp3[1];
        float rad = 1.f / (1.f + expf(-(sr + br2[0])));
        float norm = sqrtf(s0 * s0 + s1 * s1 + 1e-8f);
        float inv = rad / norm;
        out[(size_t)i * 2 + 0] = s0 * inv;
        out[(size_t)i * 2 + 1] = s1 * inv;
    }
}

// ---------------- launch ----------------

extern "C" void kernel_launch(void* const* d_in, const int* in_sizes, int n_in,
                              void* d_out, int out_size, void* d_ws, size_t ws_size,
                              hipStream_t stream) {
    (void)in_sizes; (void)n_in; (void)out_size; (void)ws_size;

    const float* x    = (const float*)d_in[0];
    const int*   ei   = (const int*)d_in[1];
    const float* W_in = (const float*)d_in[2];
    const float* b_in = (const float*)d_in[3];
    const float* Wc   = (const float*)d_in[4];
    const float* bc   = (const float*)d_in[5];
    const float* Wp1  = (const float*)d_in[6];
    const float* bp1  = (const float*)d_in[7];
    const float* Wp2  = (const float*)d_in[8];
    const float* bp2  = (const float*)d_in[9];
    const float* Wp3  = (const float*)d_in[10];
    const float* bp3  = (const float*)d_in[11];
    const float* Wr1  = (const float*)d_in[12];
    const float* br1  = (const float*)d_in[13];
    const float* Wr2  = (const float*)d_in[14];
    const float* br2  = (const float*)d_in[15];
    float* out = (float*)d_out;

    char* ws = (char*)d_ws;
    float*     m        = (float*)    (ws + 0);            // 38,400,000
    float*     p2buf    = (float*)    (ws + 0);            // aliases m (dead after aggs)
    float*     r1buf    = (float*)    (ws + 19200000);     // aliases m upper half
    _Float16*  m16      = (_Float16*) (ws + 38400000);     // 19,200,000
    _Float16*  h_hi     = (_Float16*) (ws + 57600000);     // 19,200,000
    _Float16*  h_lo     = (_Float16*) (ws + 76800000);     // 19,200,000
    _Float16*  p1_hi    = (_Float16*) (ws + 96000000);     // 19,200,000
    _Float16*  p1_lo    = (_Float16*) (ws + 115200000);    // 19,200,000
    float*     dis      = (float*)    (ws + 134400000);    //    200,000
    int*       cnt      = (int*)      (ws + 134600000);    //    200,000
    int*       cnt2     = (int*)      (ws + 134800000);    //    200,000
    int2*      adjp     = (int2*)     (ws + 135000000);    // 25,600,000
    _Float16*  Wc_hi    = (_Float16*) (ws + 160600000);    // 294,912
    _Float16*  Wc_lo    = (_Float16*) (ws + 160894912);    // 294,912
    _Float16*  Wp1_hi   = (_Float16*) (ws + 161189824);    //  73,728
    _Float16*  Wp1_lo   = (_Float16*) (ws + 161263552);    //  73,728
    _Float16*  Wp2_hi   = (_Float16*) (ws + 161337280);    //  36,864
    _Float16*  Wp2_lo   = (_Float16*) (ws + 161374144);    //  36,864
    _Float16*  Wr1_hi   = (_Float16*) (ws + 161411008);    //  36,864
    _Float16*  Wr1_lo   = (_Float16*) (ws + 161447872);    //  36,864
    // total 161,484,736 bytes

    hipMemsetAsync(cnt, 0, 400000, stream);  // cnt + cnt2 (adjacent)

    const int EB = (N_EDGES + 255) / 256;
    const int NB = (N_NODES + 255) / 256;

    k_count<<<EB, 256, 0, stream>>>(ei, cnt);
    k_dis<<<NB, 256, 0, stream>>>(cnt, dis);
    k_fill<<<EB, 256, 0, stream>>>(ei, dis, cnt2, adjp);

    k_wprep<<<(221184 + 255) / 256, 256, 0, stream>>>(
        Wc, Wp1, Wp2, Wr1, Wc_hi, Wc_lo, Wp1_hi, Wp1_lo,
        Wp2_hi, Wp2_lo, Wr1_hi, Wr1_lo);

    k_in<<<N_NODES, H, 0, stream>>>(x, W_in, b_in, h_hi, h_lo);

    const int GB2 = (NPAIRS + 3) / 4;  // 391 blocks, 4 waves (2 tiles each)
    for (int l = 0; l < 4; ++l) {
        k_mfma_gemm<12, false, false, false, true><<<GB2, 256, 0, stream>>>(
            h_hi, h_lo, Wc_hi + (size_t)l * H * H, Wc_lo + (size_t)l * H * H,
            nullptr, m, nullptr, nullptr, m16);
        k_agg<<<N_NODES / 4, 256, 0, stream>>>(m, m16, h_hi, h_lo, adjp,
                                               cnt, dis, bc + (size_t)l * H);
    }

    // heads
    k_mfma_gemm<12, true, true, true, false><<<GB2, 256, 0, stream>>>(
        h_hi, h_lo, Wp1_hi, Wp1_lo, bp1, nullptr, p1_hi, p1_lo, nullptr);
    k_mfma_gemm<6, true, true, false, false><<<GB2, 256, 0, stream>>>(
        p1_hi, p1_lo, Wp2_hi, Wp2_lo, bp2, p2buf, nullptr, nullptr, nullptr);
    k_mfma_gemm<6, true, true, false, false><<<GB2, 256, 0, stream>>>(
        h_hi, h_lo, Wr1_hi, Wr1_lo, br1, r1buf, nullptr, nullptr, nullptr);

    k_final<<<N_NODES / 4, 256, 0, stream>>>(p2buf, r1buf, Wp3, bp3, Wr2, br2, out);
}

// Round 16
// 656.554 us; speedup vs baseline: 1.7504x; 1.2225x over previous
//
#include <hip/hip_runtime.h>
#include <hip/hip_bf16.h>
#include <math.h>

#define N_NODES 50000
#define N_EDGES 800000
#define DIN 41
#define H 192
#define CAP 64
#define NTILES 3125   // 50000 / 16
#define NPAIRS 1563   // ceil(3125 / 2) -- 32-node wave tiles

typedef __attribute__((ext_vector_type(8))) _Float16 f16x8;
typedef __attribute__((ext_vector_type(4))) float f32x4;

// ---------------- graph prep ----------------

__global__ void k_count(const int* __restrict__ ei, int* __restrict__ cnt) {
    int e = blockIdx.x * blockDim.x + threadIdx.x;
    if (e < N_EDGES) atomicAdd(&cnt[ei[N_EDGES + e]], 1);
}

__global__ void k_dis(const int* __restrict__ cnt, float* __restrict__ dis) {
    int i = blockIdx.x * blockDim.x + threadIdx.x;
    if (i < N_NODES) dis[i] = rsqrtf((float)(cnt[i] + 1));  // +1 self-loop
}

// packed adjacency entry: .x = src node, .y = coef bits
__global__ void k_fill(const int* __restrict__ ei, const float* __restrict__ dis,
                       int* __restrict__ cnt2, int2* __restrict__ adjp) {
    int e = blockIdx.x * blockDim.x + threadIdx.x;
    if (e >= N_EDGES) return;
    int s = ei[e];
    int d = ei[N_EDGES + e];
    int slot = atomicAdd(&cnt2[d], 1);
    if (slot < CAP) {
        adjp[d * CAP + slot] = make_int2(s, __float_as_int(dis[s] * dis[d]));
    }
}

// ---------------- fused weight prep: [K][N] fp32 -> [N][K] fp16 hi/lo ----------------

__global__ void k_wprep(const float* __restrict__ Wc, const float* __restrict__ Wp1,
                        const float* __restrict__ Wp2, const float* __restrict__ Wr1,
                        _Float16* __restrict__ Wc_hi, _Float16* __restrict__ Wc_lo,
                        _Float16* __restrict__ Wp1_hi, _Float16* __restrict__ Wp1_lo,
                        _Float16* __restrict__ Wp2_hi, _Float16* __restrict__ Wp2_lo,
                        _Float16* __restrict__ Wr1_hi, _Float16* __restrict__ Wr1_lo) {
    int idx = blockIdx.x * blockDim.x + threadIdx.x;
    const float* src; _Float16 *hi, *lo; int K, N, off;
    if (idx < 147456) {            // 4 x 36864
        int l = idx / 36864; off = idx - l * 36864;
        src = Wc + l * 36864; hi = Wc_hi + l * 36864; lo = Wc_lo + l * 36864; K = 192; N = 192;
    } else if (idx < 184320) {     // Wp1
        off = idx - 147456; src = Wp1; hi = Wp1_hi; lo = Wp1_lo; K = 192; N = 192;
    } else if (idx < 202752) {     // Wp2
        off = idx - 184320; src = Wp2; hi = Wp2_hi; lo = Wp2_lo; K = 192; N = 96;
    } else if (idx < 221184) {     // Wr1
        off = idx - 202752; src = Wr1; hi = Wr1_hi; lo = Wr1_lo; K = 192; N = 96;
    } else return;
    int n = off / K, k = off - n * K;
    float w = src[k * N + n];
    _Float16 h16 = (_Float16)w;
    hi[off] = h16;
    lo[off] = (_Float16)(w - (float)h16);
}

// ---------------- input projection: h = x @ W_in + b_in (fp16 split only) ----------------

__global__ void k_in(const float* __restrict__ x, const float* __restrict__ W,
                     const float* __restrict__ b,
                     _Float16* __restrict__ hhi, _Float16* __restrict__ hlo) {
    __shared__ float xs[DIN];
    int i = blockIdx.x;
    int j = threadIdx.x;
    if (j < DIN) xs[j] = x[i * DIN + j];
    __syncthreads();
    float acc = b[j];
#pragma unroll
    for (int k = 0; k < DIN; ++k) acc = fmaf(xs[k], W[k * H + j], acc);
    _Float16 v16 = (_Float16)acc;
    hhi[i * H + j] = v16;
    hlo[i * H + j] = (_Float16)(acc - (float)v16);
}

// ---------------- MFMA GEMM (fp16 dual-split, ~fp32 accuracy) ----------------
// Two 16-node tiles per wave (round 12: B reuse, -200us) + LDS-staged B:
// the per-kt B slice (NROWS x 32 halfs, hi+lo) is loaded from L2 ONCE PER
// BLOCK (4 waves share) into a double-buffered LDS tile, replacing each
// wave's 144 dependent ~200cyc L2 loads with ~12cyc ds_reads. XOR swizzle
// p' = p ^ ((n>>1)&3) makes the fragment ds_read_b128 2-way (free, m136);
// linear layout would be 8-way. Global loads for kt+1 issue before kt's
// MFMAs; one barrier per kt. Per-acc MFMA order unchanged -> bit-identical.

template <int NT, bool RELU, bool BIAS, bool SPLIT_OUT, bool F16COPY>
__global__ __launch_bounds__(256) void k_mfma_gemm(
    const _Float16* __restrict__ Ahi, const _Float16* __restrict__ Alo,
    const _Float16* __restrict__ Bhi, const _Float16* __restrict__ Blo,
    const float* __restrict__ bias, float* __restrict__ Cf,
    _Float16* __restrict__ Chi, _Float16* __restrict__ Clo,
    _Float16* __restrict__ C16) {
    constexpr int NROWS = NT * 16;          // B rows staged per kt slice
    constexpr int CHUNKS = NROWS * 4;       // 16-B chunks per (hi|lo) slice
    constexpr int PT = (CHUNKS + 255) / 256;
    __shared__ _Float16 ldsB[2][2][NROWS * 32];   // [buf][hi/lo][n*32+k]

    const int wave = threadIdx.x >> 6;
    const int lane = threadIdx.x & 63;
    int q = blockIdx.x * 4 + wave;          // tile-pair index
    if (q >= NPAIRS) q = NPAIRS - 1;        // clamp (no early return: barriers)
    const int t0 = 2 * q;
    const int t1 = 2 * q + 1;
    const bool has2 = (t1 < NTILES);
    const int row16 = lane & 15;
    const int kb = lane >> 4;               // 0..3
    const long base0 = (long)t0 * 16;
    const long base1 = has2 ? (long)t1 * 16 : base0;

    f16x8 sh[PT], sl[PT];
    // stage-load slice kt into regs (coalesced 16B chunks)
    auto LOADC = [&](int kt) {
#pragma unroll
        for (int u = 0; u < PT; ++u) {
            int c = (int)threadIdx.x + u * 256;
            if (c < CHUNKS) {
                int n = c >> 2, p = c & 3;
                long g = (long)n * H + kt * 32 + p * 8;
                sh[u] = *(const f16x8*)(Bhi + g);
                sl[u] = *(const f16x8*)(Blo + g);
            }
        }
    };
    // regs -> LDS with XOR-swizzled 16B sub-chunk position
    auto STOREC = [&](int buf) {
#pragma unroll
        for (int u = 0; u < PT; ++u) {
            int c = (int)threadIdx.x + u * 256;
            if (c < CHUNKS) {
                int n = c >> 2, p = c & 3;
                int sp = p ^ ((n >> 1) & 3);
                *(f16x8*)((char*)&ldsB[buf][0][0] + n * 64 + sp * 16) = sh[u];
                *(f16x8*)((char*)&ldsB[buf][1][0] + n * 64 + sp * 16) = sl[u];
            }
        }
    };

    f32x4 acc0[NT], acc1[NT];
#pragma unroll
    for (int nt = 0; nt < NT; ++nt) {
        acc0[nt] = (f32x4){0.f, 0.f, 0.f, 0.f};
        acc1[nt] = (f32x4){0.f, 0.f, 0.f, 0.f};
    }

    LOADC(0);
    STOREC(0);
    __syncthreads();

    const int swz = (row16 >> 1) & 3;       // fragment-read swizzle (matches store)

#pragma unroll
    for (int kt = 0; kt < 6; ++kt) {
        const int buf = kt & 1;
        if (kt < 5) LOADC(kt + 1);          // next slice's globals in flight

        const long aoff0 = (base0 + row16) * H + kb * 8 + kt * 32;
        const long aoff1 = (base1 + row16) * H + kb * 8 + kt * 32;
        f16x8 a0h = *(const f16x8*)(Ahi + aoff0);
        f16x8 a0l = *(const f16x8*)(Alo + aoff0);
        f16x8 a1h = *(const f16x8*)(Ahi + aoff1);
        f16x8 a1l = *(const f16x8*)(Alo + aoff1);

        const char* bh = (const char*)&ldsB[buf][0][0];
        const char* bl = (const char*)&ldsB[buf][1][0];
#pragma unroll
        for (int nt = 0; nt < NT; ++nt) {
            const int off = (nt * 16 + row16) * 64 + (((kb ^ swz)) * 16);
            f16x8 bhf = *(const f16x8*)(bh + off);
            f16x8 blf = *(const f16x8*)(bl + off);
            acc0[nt] = __builtin_amdgcn_mfma_f32_16x16x32_f16(a0h, bhf, acc0[nt], 0, 0, 0);
            acc0[nt] = __builtin_amdgcn_mfma_f32_16x16x32_f16(a0l, bhf, acc0[nt], 0, 0, 0);
            acc0[nt] = __builtin_amdgcn_mfma_f32_16x16x32_f16(a0h, blf, acc0[nt], 0, 0, 0);
            acc1[nt] = __builtin_amdgcn_mfma_f32_16x16x32_f16(a1h, bhf, acc1[nt], 0, 0, 0);
            acc1[nt] = __builtin_amdgcn_mfma_f32_16x16x32_f16(a1l, bhf, acc1[nt], 0, 0, 0);
            acc1[nt] = __builtin_amdgcn_mfma_f32_16x16x32_f16(a1h, blf, acc1[nt], 0, 0, 0);
        }

        if (kt < 5) STOREC(buf ^ 1);        // write next slice (other buffer)
        __syncthreads();
    }

#pragma unroll
    for (int nt = 0; nt < NT; ++nt) {
        const int n = nt * 16 + row16;
        const float bs = BIAS ? bias[n] : 0.f;
#pragma unroll
        for (int r = 0; r < 4; ++r) {
            long node = base0 + kb * 4 + r;
            float v = acc0[nt][r] + bs;
            if (RELU) v = fmaxf(v, 0.f);
            if (SPLIT_OUT) {
                _Float16 v16 = (_Float16)v;
                Chi[node * (NT * 16) + n] = v16;
                Clo[node * (NT * 16) + n] = (_Float16)(v - (float)v16);
            } else {
                Cf[node * (NT * 16) + n] = v;
                if (F16COPY) C16[node * (NT * 16) + n] = (_Float16)v;
            }
        }
        if (has2) {
#pragma unroll
            for (int r = 0; r < 4; ++r) {
                long node = base1 + kb * 4 + r;
                float v = acc1[nt][r] + bs;
                if (RELU) v = fmaxf(v, 0.f);
                if (SPLIT_OUT) {
                    _Float16 v16 = (_Float16)v;
                    Chi[node * (NT * 16) + n] = v16;
                    Clo[node * (NT * 16) + n] = (_Float16)(v - (float)v16);
                } else {
                    Cf[node * (NT * 16) + n] = v;
                    if (F16COPY) C16[node * (NT * 16) + n] = (_Float16)v;
                }
            }
        }
    }
}

// ---------------- aggregation (round 14 verified: 77.5us, FETCH 172MB) ----------------

__global__ __launch_bounds__(256, 4) void k_agg(
    const float* __restrict__ m, const _Float16* __restrict__ m16,
    _Float16* __restrict__ hhi, _Float16* __restrict__ hlo,
    const int2* __restrict__ adjp,
    const int* __restrict__ cnt, const float* __restrict__ dis,
    const float* __restrict__ bc) {
    int gid = blockIdx.x * blockDim.x + threadIdx.x;
    int i = gid >> 6;
    int lane = threadIdx.x & 63;
    if (i >= N_NODES) return;

    float disi = dis[i];
    float selfc = disi * disi;
    const float* mi = m + (size_t)i * H;
    float a0 = selfc * mi[lane];
    float a1 = selfc * mi[lane + 64];
    float a2 = selfc * mi[lane + 128];

    int c = cnt[i];
    if (c > CAP) c = CAP;
    const int2* ap = adjp + (size_t)i * CAP;

    for (int e0 = 0; e0 < c; e0 += 16) {
        int off[16];
        float cf[16];
#pragma unroll
        for (int u = 0; u < 16; ++u) {
            bool ok = (e0 + u) < c;
            int idx = ok ? (e0 + u) : 0;
            int2 ent = ap[idx];
            off[u] = ent.x * H + lane;
            cf[u] = ok ? __int_as_float(ent.y) : 0.f;
        }
        float v0[16], v1[16], v2[16];
#pragma unroll
        for (int u = 0; u < 16; ++u) {
            v0[u] = (float)m16[off[u]];
            v1[u] = (float)m16[off[u] + 64];
            v2[u] = (float)m16[off[u] + 128];
        }
#pragma unroll
        for (int u = 0; u < 16; ++u) {
            a0 = fmaf(cf[u], v0[u], a0);
            a1 = fmaf(cf[u], v1[u], a1);
            a2 = fmaf(cf[u], v2[u], a2);
        }
    }

    size_t base = (size_t)i * H;
#pragma unroll
    for (int q = 0; q < 3; ++q) {
        size_t off = base + lane + q * 64;
        float agg = (q == 0) ? a0 : (q == 1) ? a1 : a2;
        float hv = (float)hhi[off] + (float)hlo[off] + fmaxf(agg + bc[lane + q * 64], 0.f);
        _Float16 t = (_Float16)hv;
        hhi[off] = t;
        hlo[off] = (_Float16)(hv - (float)t);
    }
}

// ---------------- final heads tail + normalize ----------------

__global__ void k_final(const float* __restrict__ p2, const float* __restrict__ r1,
                        const float* __restrict__ Wp3, const float* __restrict__ bp3,
                        const float* __restrict__ Wr2, const float* __restrict__ br2,
                        float* __restrict__ out) {
    int gid = blockIdx.x * blockDim.x + threadIdx.x;
    int i = gid >> 6;
    int lane = threadIdx.x & 63;
    if (i >= N_NODES) return;

    float s0 = 0.f, s1 = 0.f, sr = 0.f;
    for (int k = lane; k < 96; k += 64) {
        float pv = p2[(size_t)i * 96 + k];
        s0 = fmaf(pv, Wp3[k * 2 + 0], s0);
        s1 = fmaf(pv, Wp3[k * 2 + 1], s1);
        float rv = r1[(size_t)i * 96 + k];
        sr = fmaf(rv, Wr2[k], sr);
    }
#pragma unroll
    for (int off = 32; off > 0; off >>= 1) {
        s0 += __shfl_xor(s0, off);
        s1 += __shfl_xor(s1, off);
        sr += __shfl_xor(sr, off);
    }
    if (lane == 0) {
        s0 += bp3[0];
        s1 += bp3[1];
        float rad = 1.f / (1.f + expf(-(sr + br2[0])));
        float norm = sqrtf(s0 * s0 + s1 * s1 + 1e-8f);
        float inv = rad / norm;
        out[(size_t)i * 2 + 0] = s0 * inv;
        out[(size_t)i * 2 + 1] = s1 * inv;
    }
}

// ---------------- launch ----------------

extern "C" void kernel_launch(void* const* d_in, const int* in_sizes, int n_in,
                              void* d_out, int out_size, void* d_ws, size_t ws_size,
                              hipStream_t stream) {
    (void)in_sizes; (void)n_in; (void)out_size; (void)ws_size;

    const float* x    = (const float*)d_in[0];
    const int*   ei   = (const int*)d_in[1];
    const float* W_in = (const float*)d_in[2];
    const float* b_in = (const float*)d_in[3];
    const float* Wc   = (const float*)d_in[4];
    const float* bc   = (const float*)d_in[5];
    const float* Wp1  = (const float*)d_in[6];
    const float* bp1  = (const float*)d_in[7];
    const float* Wp2  = (const float*)d_in[8];
    const float* bp2  = (const float*)d_in[9];
    const float* Wp3  = (const float*)d_in[10];
    const float* bp3  = (const float*)d_in[11];
    const float* Wr1  = (const float*)d_in[12];
    const float* br1  = (const float*)d_in[13];
    const float* Wr2  = (const float*)d_in[14];
    const float* br2  = (const float*)d_in[15];
    float* out = (float*)d_out;

    char* ws = (char*)d_ws;
    float*     m        = (float*)    (ws + 0);            // 38,400,000
    float*     p2buf    = (float*)    (ws + 0);            // aliases m (dead after aggs)
    float*     r1buf    = (float*)    (ws + 19200000);     // aliases m upper half
    _Float16*  m16      = (_Float16*) (ws + 38400000);     // 19,200,000
    _Float16*  h_hi     = (_Float16*) (ws + 57600000);     // 19,200,000
    _Float16*  h_lo     = (_Float16*) (ws + 76800000);     // 19,200,000
    _Float16*  p1_hi    = (_Float16*) (ws + 96000000);     // 19,200,000
    _Float16*  p1_lo    = (_Float16*) (ws + 115200000);    // 19,200,000
    float*     dis      = (float*)    (ws + 134400000);    //    200,000
    int*       cnt      = (int*)      (ws + 134600000);    //    200,000
    int*       cnt2     = (int*)      (ws + 134800000);    //    200,000
    int2*      adjp     = (int2*)     (ws + 135000000);    // 25,600,000
    _Float16*  Wc_hi    = (_Float16*) (ws + 160600000);    // 294,912
    _Float16*  Wc_lo    = (_Float16*) (ws + 160894912);    // 294,912
    _Float16*  Wp1_hi   = (_Float16*) (ws + 161189824);    //  73,728
    _Float16*  Wp1_lo   = (_Float16*) (ws + 161263552);    //  73,728
    _Float16*  Wp2_hi   = (_Float16*) (ws + 161337280);    //  36,864
    _Float16*  Wp2_lo   = (_Float16*) (ws + 161374144);    //  36,864
    _Float16*  Wr1_hi   = (_Float16*) (ws + 161411008);    //  36,864
    _Float16*  Wr1_lo   = (_Float16*) (ws + 161447872);    //  36,864
    // total 161,484,736 bytes

    hipMemsetAsync(cnt, 0, 400000, stream);  // cnt + cnt2 (adjacent)

    const int EB = (N_EDGES + 255) / 256;
    const int NB = (N_NODES + 255) / 256;

    k_count<<<EB, 256, 0, stream>>>(ei, cnt);
    k_dis<<<NB, 256, 0, stream>>>(cnt, dis);
    k_fill<<<EB, 256, 0, stream>>>(ei, dis, cnt2, adjp);

    k_wprep<<<(221184 + 255) / 256, 256, 0, stream>>>(
        Wc, Wp1, Wp2, Wr1, Wc_hi, Wc_lo, Wp1_hi, Wp1_lo,
        Wp2_hi, Wp2_lo, Wr1_hi, Wr1_lo);

    k_in<<<N_NODES, H, 0, stream>>>(x, W_in, b_in, h_hi, h_lo);

    const int GB2 = (NPAIRS + 3) / 4;  // 391 blocks, 4 waves (2 tiles each)
    for (int l = 0; l < 4; ++l) {
        k_mfma_gemm<12, false, false, false, true><<<GB2, 256, 0, stream>>>(
            h_hi, h_lo, Wc_hi + (size_t)l * H * H, Wc_lo + (size_t)l * H * H,
            nullptr, m, nullptr, nullptr, m16);
        k_agg<<<N_NODES / 4, 256, 0, stream>>>(m, m16, h_hi, h_lo, adjp,
                                               cnt, dis, bc + (size_t)l * H);
    }

    // heads
    k_mfma_gemm<12, true, true, true, false><<<GB2, 256, 0, stream>>>(
        h_hi, h_lo, Wp1_hi, Wp1_lo, bp1, nullptr, p1_hi, p1_lo, nullptr);
    k_mfma_gemm<6, true, true, false, false><<<GB2, 256, 0, stream>>>(
        p1_hi, p1_lo, Wp2_hi, Wp2_lo, bp2, p2buf, nullptr, nullptr, nullptr);
    k_mfma_gemm<6, true, true, false, false><<<GB2, 256, 0, stream>>>(
        h_hi, h_lo, Wr1_hi, Wr1_lo, br1, r1buf, nullptr, nullptr, nullptr);

    k_final<<<N_NODES / 4, 256, 0, stream>>>(p2buf, r1buf, Wp3, bp3, Wr2, br2, out);
}